// Round 1
// baseline (251.914 us; speedup 1.0000x reference)
//
#include <hip/hip_runtime.h>
#include <math.h>

// Problem constants
//  B=64, CH=64, T_IN=32, N_OSC=32, BAND=16384, N_NOISE_FRAMES=4096, NOISE_STEP=4
//  N_UP=7, LOWEST_FREQ = 20/11025
#define LOWEST_FREQ_F 0.00181405895691609977f

typedef short bf16x8 __attribute__((ext_vector_type(8)));
typedef float f32x16 __attribute__((ext_vector_type(16)));

__device__ __forceinline__ float lrelu(float x) { return x > 0.f ? x : 0.2f * x; }
__device__ __forceinline__ float sin_rev(float fr) { return __builtin_amdgcn_sinf(fr); }
__device__ __forceinline__ float bf2f(unsigned short u) {
  union { unsigned int i; float f; } x; x.i = ((unsigned int)u) << 16; return x.f;
}
__device__ __forceinline__ unsigned short f2bf(float f) {
  union { float f; unsigned int i; } x; x.f = f;
  unsigned int r = x.i + 0x7FFFu + ((x.i >> 16) & 1u);   // RNE
  return (unsigned short)(r >> 16);
}
__device__ __forceinline__ unsigned int pack2(float a, float b) {
  return (unsigned int)f2bf(a) | ((unsigned int)f2bf(b) << 16);
}

// ---------------------------------------------------------------------------
// prep: transpose frontend weights (net x4 + fin) -> wtF[l][(ci*3+k)][co],
//       amp/frq -> awfwT[c2][o][4] = (aw[2c2],fw[2c2],aw[2c2+1],fw[2c2+1]),
//       nz_init -> [c][o], fold noise conv weights -> bf16
//       wfold[l][pd][co][ci]  (pd: 0=w0, 1=w1+w2, 2=w0+w1, 3=w2)
// ---------------------------------------------------------------------------
__global__ __launch_bounds__(256) void prep_kernel(
    const float* __restrict__ net_w, const float* __restrict__ fin_w,
    const float* __restrict__ amp_w, const float* __restrict__ frq_w,
    const float* __restrict__ nzi_w, const float* __restrict__ nzu_w,
    float* __restrict__ wtF, float* __restrict__ awfwT,
    float* __restrict__ nzT, short* __restrict__ wfold)
{
  int idx = blockIdx.x * 256 + threadIdx.x;
  if (idx < 61440) {                       // 5 * 12288
    int l = idx / 12288, r = idx - l * 12288;   // r = row*64 + co
    int row = r >> 6, co = r & 63;              // row = ci*3+k
    const float* src = (l < 4) ? (net_w + l * 12288) : fin_w;
    wtF[idx] = src[co * 192 + row];
  } else if (idx < 65536) {                // awfwT: 4096 floats, [c2][o][4]
    int r = idx - 61440;
    int c2 = r >> 7, rem = r & 127, o = rem >> 2, k = rem & 3;
    int c = c2 * 2 + (k >> 1);
    awfwT[r] = (k & 1) ? frq_w[o * 64 + c] : amp_w[o * 64 + c];
  } else if (idx < 69632) {                // nzT: 4096
    int r = idx - 65536; int c = r >> 6, o = r & 63;
    nzT[r] = nzi_w[o * 64 + c];
  } else if (idx < 69632 + 114688) {       // wfold: 7*16384
    int r = idx - 69632;
    int l = r >> 14, q = r & 16383;
    int pd = q >> 12, co = (q >> 6) & 63, ci = q & 63;
    const float* wb = nzu_w + l * 12288 + co * 192 + ci * 3;
    float v;
    if      (pd == 0) v = wb[0];
    else if (pd == 1) v = wb[1] + wb[2];
    else if (pd == 2) v = wb[0] + wb[1];
    else              v = wb[2];
    wfold[r] = (short)f2bf(v);
  }
}

// ---------------------------------------------------------------------------
// In-LDS MFMA noise layer (even/odd folded up-conv + leaky), 16-wave version.
// tin rows = sample+1 (halos 0 and TIN+1 zero), 64 cols, stride 72 shorts.
// Ends with __syncthreads.
// v_mfma_f32_32x32x16_bf16 (HW-verified): A[m=L&31][k=(L>>5)*8+j],
// B[k][n=L&31], D col=L&31, row=(r&3)+8*(r>>2)+4*(L>>5).
// ---------------------------------------------------------------------------
template<int TIN>
__device__ __forceinline__ void noise_layer(
    const short* tin, short* tout, const short* __restrict__ wf,
    const float* __restrict__ bias, int tid)
{
  const int L  = tid & 63;
  const int w  = tid >> 6;        // 0..15
  const int mt = w & 1;
  const int ng = w >> 1;          // 0..7

  bf16x8 Af[4][4];
  {
    const short* wb = wf + (mt*32 + (L & 31))*64 + ((L >> 5) << 3);
    #pragma unroll
    for (int pd = 0; pd < 4; ++pd)
      #pragma unroll
      for (int ks = 0; ks < 4; ++ks)
        Af[pd][ks] = *(const bf16x8*)(wb + pd*4096 + ks*16);
  }
  f32x16 binit;
  #pragma unroll
  for (int r = 0; r < 16; ++r)
    binit[r] = bias[mt*32 + (r & 3) + 8*(r >> 2) + 4*(L >> 5)];

  if (tid < 64) { tout[tid] = 0; tout[(2*TIN + 1)*72 + tid] = 0; }

  constexpr int TOT = TIN / 32;          // n-tiles total
  constexpr int NPG = (TOT + 7) / 8;     // n-tiles per ng group (8 groups)
  #pragma unroll
  for (int nt = 0; nt < NPG; ++nt) {
    int ntile = ng*NPG + nt;
    if (ntile < TOT) {
      int s = ntile*32 + (L & 31);
      const short* bp = tin + s*72 + ((L >> 5) << 3);   // row s = sample s-1
      f32x16 Ce = binit, Co = binit;
      #pragma unroll
      for (int ks = 0; ks < 4; ++ks) {
        bf16x8 Bm = *(const bf16x8*)(bp + ks*16);
        bf16x8 B0 = *(const bf16x8*)(bp + 72 + ks*16);
        bf16x8 Bp = *(const bf16x8*)(bp + 144 + ks*16);
        Ce = __builtin_amdgcn_mfma_f32_32x32x16_bf16(Af[0][ks], Bm, Ce, 0, 0, 0);
        Ce = __builtin_amdgcn_mfma_f32_32x32x16_bf16(Af[1][ks], B0, Ce, 0, 0, 0);
        Co = __builtin_amdgcn_mfma_f32_32x32x16_bf16(Af[2][ks], B0, Co, 0, 0, 0);
        Co = __builtin_amdgcn_mfma_f32_32x32x16_bf16(Af[3][ks], Bp, Co, 0, 0, 0);
      }
      #pragma unroll
      for (int q4 = 0; q4 < 4; ++q4) {
        int co0 = mt*32 + 8*q4 + 4*(L >> 5);
        uint2 ve, vo;
        ve.x = pack2(lrelu(Ce[4*q4+0]), lrelu(Ce[4*q4+1]));
        ve.y = pack2(lrelu(Ce[4*q4+2]), lrelu(Ce[4*q4+3]));
        vo.x = pack2(lrelu(Co[4*q4+0]), lrelu(Co[4*q4+1]));
        vo.y = pack2(lrelu(Co[4*q4+2]), lrelu(Co[4*q4+3]));
        *(uint2*)&tout[(2*s + 1)*72 + co0] = ve;
        *(uint2*)&tout[(2*s + 2)*72 + co0] = vo;
      }
    }
  }
  __syncthreads();
}

// ---------------------------------------------------------------------------
// z_front: 1024 threads/block, one block per batch (16 waves/CU for latency
// hiding). f32 conv stack (each thread 2 samples, bitwise-identical FMA chain
// to the 512-thread version), nz_init -> y0 (bf16 tile), amp/freq from paired
// b128 weights + z-transpose tile, fp64 phase boundaries on idle wave 15,
// noise layers 0..4 (T 32->1024), layer 4 writes y5 [b][t][co] to global.
// ---------------------------------------------------------------------------
__global__ __launch_bounds__(1024) void z_front(
    const float* __restrict__ x, const float* __restrict__ wtF,
    const float* __restrict__ net_b, const float* __restrict__ fin_b,
    const float* __restrict__ awfwT, const float* __restrict__ amp_b,
    const float* __restrict__ frq_b,
    const float* __restrict__ nzT, const float* __restrict__ nzi_b,
    const short* __restrict__ wfold, const float* __restrict__ nzu_b,
    unsigned short* __restrict__ y5, float* __restrict__ amp_o,
    float* __restrict__ frq_o, float* __restrict__ ph_o)
{
  // arena (134112 B):
  //  phase C/D: tileA [0,18720) | tileB [18720,55872) | tileC [55872,129888)
  //  phase A/B overlays: wbuf 49152 @0 | za 9216 @49152 | zb 9216 @58368
  //                      zt 8448 @67584 | awL 16384 @76032 | nzL 16384 @92416
  //  fl 4224 @129888 (disjoint from everything, live through phase C)
  __shared__ __align__(16) char arena[134112];
  short* tileA = (short*)arena;
  short* tileB = (short*)(arena + 18720);
  short* tileC = (short*)(arena + 55872);
  float* wbuf  = (float*)arena;
  float* za    = (float*)(arena + 49152);
  float* zb    = (float*)(arena + 58368);
  float* zt    = (float*)(arena + 67584);
  float* awL   = (float*)(arena + 76032);
  float* nzL   = (float*)(arena + 92416);
  float* fl    = (float*)(arena + 129888);

  const int b   = blockIdx.x;
  const int tid = threadIdx.x;
  const int co  = tid & 63;
  const int wv  = tid >> 6;   // 0..15, fixed per wave

  // stage layer-0 weights + input + small weight tables
  float4 pf[3];
  #pragma unroll
  for (int i = 0; i < 3; ++i) pf[i] = ((const float4*)wtF)[tid + i*1024];
  for (int idx = tid; idx < 2048; idx += 1024) {
    int t = idx >> 6, c = idx & 63;
    za[c*36 + t + 1] = x[b*2048 + idx];
  }
  if (tid < 64) {
    za[tid*36] = 0.f; za[tid*36 + 33] = 0.f;
    zb[tid*36] = 0.f; zb[tid*36 + 33] = 0.f;
  }
  ((float4*)awL)[tid] = ((const float4*)awfwT)[tid];   // 1024 x f4 = 16KB
  ((float4*)nzL)[tid] = ((const float4*)nzT)[tid];     // 1024 x f4 = 16KB
  #pragma unroll
  for (int i = 0; i < 3; ++i) ((float4*)wbuf)[tid + i*1024] = pf[i];
  __syncthreads();

  float* pa = za;
  float* pb = zb;
  const int tg = wv;           // t-group: t = tg*2 + j
  for (int l = 0; l < 5; ++l) {
    if (l < 4) {   // prefetch next layer's weights into registers
      #pragma unroll
      for (int i = 0; i < 3; ++i)
        pf[i] = ((const float4*)wtF)[(l+1)*3072 + tid + i*1024];
    }
    float bv = (l < 4) ? net_b[l*64 + co] : fin_b[co];
    float a0 = bv, a1 = bv;
    for (int ci = 0; ci < 64; ++ci) {
      const float* row = pa + ci*36 + tg*2;
      float2 u0 = *(const float2*)(row);
      float2 u1 = *(const float2*)(row + 2);
      float w0 = wbuf[(ci*3+0)*64 + co];
      float w1 = wbuf[(ci*3+1)*64 + co];
      float w2 = wbuf[(ci*3+2)*64 + co];
      a0 = fmaf(w0, u0.x, a0); a0 = fmaf(w1, u0.y, a0); a0 = fmaf(w2, u1.x, a0);
      a1 = fmaf(w0, u0.y, a1); a1 = fmaf(w1, u1.x, a1); a1 = fmaf(w2, u1.y, a1);
    }
    if (l < 4) {
      pb[co*36 + tg*2 + 1] = lrelu(a0);
      pb[co*36 + tg*2 + 2] = lrelu(a1);
    } else {
      int t0 = tg*2;                  // final z stored WITHOUT halo shift
      pb[co*36 + t0]     = a0;
      pb[co*36 + t0 + 1] = a1;
      zt[t0*66 + co]       = a0;      // transposed copy for proj
      zt[(t0+1)*66 + co]   = a1;
    }
    __syncthreads();
    if (l < 4) {
      #pragma unroll
      for (int i = 0; i < 3; ++i) ((float4*)wbuf)[tid + i*1024] = pf[i];
      __syncthreads();
    }
    float* tp = pa; pa = pb; pb = tp;
  }
  const float* zf = pa;  // final z, 64ch x 32t, cols 0..31 (no halo shift)

  // ---- y0 = nz_init 1x1 conv -> bf16 into tileA rows t+1 ----
  {
    int t0 = wv*2;
    float bv0 = nzi_b[co];
    float acc0 = bv0, acc1 = bv0;
    #pragma unroll 8
    for (int c = 0; c < 64; ++c) {
      float2 zv = *(const float2*)(zf + c*36 + t0);
      float wvv = nzL[c*64 + co];
      acc0 = fmaf(wvv, zv.x, acc0);
      acc1 = fmaf(wvv, zv.y, acc1);
    }
    tileA[(t0 + 1)*72 + co] = (short)f2bf(acc0);
    tileA[(t0 + 2)*72 + co] = (short)f2bf(acc1);
  }
  if (tid < 64) { tileA[tid] = 0; tileA[33*72 + tid] = 0; }

  // ---- amp / freq projections: paired b128 weights + zt b64 reads ----
  {
    int o = tid & 31, t = tid >> 5;      // 1024 tasks, one pass
    float aa = amp_b[o], ff = frq_b[o];
    #pragma unroll 8
    for (int c2 = 0; c2 < 32; ++c2) {
      float4 w4 = *(const float4*)(awL + (c2*32 + o)*4);
      float2 zv = *(const float2*)(zt + t*66 + c2*2);
      aa = fmaf(w4.x, zv.x, aa); ff = fmaf(w4.y, zv.x, ff);
      aa = fmaf(w4.z, zv.y, aa); ff = fmaf(w4.w, zv.y, ff);
    }
    aa = fabsf(aa);
    float sg = 1.f / (1.f + expf(-ff));
    float fq = LOWEST_FREQ_F + sg * (1.f - LOWEST_FREQ_F);
    amp_o[b*1024 + o*32 + t] = aa;
    frq_o[b*1024 + o*32 + t] = fq;
    fl[o*33 + t] = fq;
  }
  __syncthreads();

  // ---- fp64 phase boundary prefix on wave 15 (idle in noise layers 0..2),
  //      overlaps MFMA work of the other waves ----
  if (wv == 15 && (tid & 63) < 32) {
    const int o = tid & 31;
    double P = 256.0 * (double)fl[o*33];
    double hd = P * 0.5;
    ph_o[b*1024 + o*32] = (float)(hd - floor(hd));
    for (int i = 1; i < 32; ++i) {
      P += 256.0 * ((double)fl[o*33 + i - 1] + (double)fl[o*33 + i]);
      hd = P * 0.5;
      ph_o[b*1024 + o*32 + i] = (float)(hd - floor(hd));
    }
  }

  // ---- noise layers 0..3 in LDS: T 32 -> 64 -> 128 -> 256 -> 512 ----
  noise_layer<32> (tileA, tileB, wfold + 0*16384, nzu_b + 0*64, tid);
  noise_layer<64> (tileB, tileA, wfold + 1*16384, nzu_b + 1*64, tid);
  noise_layer<128>(tileA, tileB, wfold + 2*16384, nzu_b + 2*64, tid);
  noise_layer<256>(tileB, tileC, wfold + 3*16384, nzu_b + 3*64, tid);

  // ---- layer 4: tileC (T=512) -> y5 global (T=1024), [b][t][co] ----
  {
    const short* wf4   = wfold + 4*16384;
    const float* bias4 = nzu_b + 4*64;
    const int L  = tid & 63;
    const int mt = wv & 1;
    const int ng = wv >> 1;     // 0..7, 2 n-tiles each (TOT=16)

    bf16x8 Af[4][4];
    {
      const short* wb = wf4 + (mt*32 + (L & 31))*64 + ((L >> 5) << 3);
      #pragma unroll
      for (int pd = 0; pd < 4; ++pd)
        #pragma unroll
        for (int ks = 0; ks < 4; ++ks)
          Af[pd][ks] = *(const bf16x8*)(wb + pd*4096 + ks*16);
    }
    f32x16 binit;
    #pragma unroll
    for (int r = 0; r < 16; ++r)
      binit[r] = bias4[mt*32 + (r & 3) + 8*(r >> 2) + 4*(L >> 5)];

    unsigned short* outb = y5 + (size_t)b * 1024 * 64;
    #pragma unroll
    for (int nt = 0; nt < 2; ++nt) {
      int s = (ng*2 + nt)*32 + (L & 31);                // 0..511
      const short* bp = tileC + s*72 + ((L >> 5) << 3); // row s = sample s-1
      f32x16 Ce = binit, Co = binit;
      #pragma unroll
      for (int ks = 0; ks < 4; ++ks) {
        bf16x8 Bm = *(const bf16x8*)(bp + ks*16);
        bf16x8 B0 = *(const bf16x8*)(bp + 72 + ks*16);
        bf16x8 Bp = *(const bf16x8*)(bp + 144 + ks*16);
        Ce = __builtin_amdgcn_mfma_f32_32x32x16_bf16(Af[0][ks], Bm, Ce, 0, 0, 0);
        Ce = __builtin_amdgcn_mfma_f32_32x32x16_bf16(Af[1][ks], B0, Ce, 0, 0, 0);
        Co = __builtin_amdgcn_mfma_f32_32x32x16_bf16(Af[2][ks], B0, Co, 0, 0, 0);
        Co = __builtin_amdgcn_mfma_f32_32x32x16_bf16(Af[3][ks], Bp, Co, 0, 0, 0);
      }
      int t0 = 2*s;
      #pragma unroll
      for (int q4 = 0; q4 < 4; ++q4) {
        int co0 = mt*32 + 8*q4 + 4*(L >> 5);
        uint2 ve, vo;
        ve.x = pack2(lrelu(Ce[4*q4+0]), lrelu(Ce[4*q4+1]));
        ve.y = pack2(lrelu(Ce[4*q4+2]), lrelu(Ce[4*q4+3]));
        vo.x = pack2(lrelu(Co[4*q4+0]), lrelu(Co[4*q4+1]));
        vo.y = pack2(lrelu(Co[4*q4+2]), lrelu(Co[4*q4+3]));
        *(uint2*)(outb + (size_t)t0*64 + co0)       = ve;
        *(uint2*)(outb + (size_t)(t0+1)*64 + co0)   = vo;
      }
    }
  }
}

// ---------------------------------------------------------------------------
// Global-to-global MFMA up-conv layer, [b][t][co] layout.
// ---------------------------------------------------------------------------
template<int STILE>
__global__ __launch_bounds__(256) void mfma_up_t(
    const unsigned short* __restrict__ in, unsigned short* __restrict__ out,
    const short* __restrict__ wf, const float* __restrict__ bias, int Tin)
{
  constexpr int ROWS = STILE + 2;
  constexpr int G    = STILE / 64;   // n-tiles per wave (n-tiles total = 2G)
  __shared__ __align__(16) short lB[ROWS * 72];

  const int b   = blockIdx.y;
  const int s0  = blockIdx.x * STILE;
  const int tid = threadIdx.x;
  const int L   = tid & 63;
  const int w   = tid >> 6;
  const int mt  = w & 1;
  const int ng  = w >> 1;

  bf16x8 Af[4][4];
  {
    const short* wb = wf + (mt*32 + (L & 31))*64 + ((L >> 5) << 3);
    #pragma unroll
    for (int pd = 0; pd < 4; ++pd)
      #pragma unroll
      for (int ks = 0; ks < 4; ++ks)
        Af[pd][ks] = *(const bf16x8*)(wb + pd*4096 + ks*16);
  }

  const unsigned short* inb = in + (size_t)b * Tin * 64;
  for (int c = tid; c < ROWS*8; c += 256) {
    int row = c >> 3, pos = (c & 7) << 3;
    int g = s0 - 1 + row;
    bf16x8 v = {0,0,0,0,0,0,0,0};
    if (g >= 0 && g < Tin) v = *(const bf16x8*)(inb + (size_t)g*64 + pos);
    *(bf16x8*)&lB[row*72 + pos] = v;
  }

  f32x16 binit;
  #pragma unroll
  for (int r = 0; r < 16; ++r)
    binit[r] = bias[mt*32 + (r & 3) + 8*(r >> 2) + 4*(L >> 5)];

  __syncthreads();

  unsigned short* outb = out + (size_t)b * (2*Tin) * 64;
  #pragma unroll
  for (int nt = 0; nt < G; ++nt) {
    int s_loc = ng*(32*G) + nt*32 + (L & 31);
    const short* bp = lB + s_loc*72 + ((L >> 5) << 3);
    f32x16 Ce = binit, Co = binit;
    #pragma unroll
    for (int ks = 0; ks < 4; ++ks) {
      bf16x8 Bm = *(const bf16x8*)(bp + ks*16);
      bf16x8 B0 = *(const bf16x8*)(bp + 72 + ks*16);
      bf16x8 Bp = *(const bf16x8*)(bp + 144 + ks*16);
      Ce = __builtin_amdgcn_mfma_f32_32x32x16_bf16(Af[0][ks], Bm, Ce, 0, 0, 0);
      Ce = __builtin_amdgcn_mfma_f32_32x32x16_bf16(Af[1][ks], B0, Ce, 0, 0, 0);
      Co = __builtin_amdgcn_mfma_f32_32x32x16_bf16(Af[2][ks], B0, Co, 0, 0, 0);
      Co = __builtin_amdgcn_mfma_f32_32x32x16_bf16(Af[3][ks], Bp, Co, 0, 0, 0);
    }
    int t0 = (s0 + s_loc) * 2;
    #pragma unroll
    for (int q4 = 0; q4 < 4; ++q4) {
      int co0 = mt*32 + 8*q4 + 4*(L >> 5);
      uint2 ve, vo;
      ve.x = pack2(lrelu(Ce[4*q4+0]), lrelu(Ce[4*q4+1]));
      ve.y = pack2(lrelu(Ce[4*q4+2]), lrelu(Ce[4*q4+3]));
      vo.x = pack2(lrelu(Co[4*q4+0]), lrelu(Co[4*q4+1]));
      vo.y = pack2(lrelu(Co[4*q4+2]), lrelu(Co[4*q4+3]));
      *(uint2*)(outb + (size_t)t0*64 + co0)     = ve;
      *(uint2*)(outb + (size_t)(t0+1)*64 + co0) = vo;
    }
  }
}

// ---------------------------------------------------------------------------
// Final fused: layer 6 (Tin=2048 -> 4096, y7 stays in LDS) + nz_final coeffs
// + squared + length-4 ortho rfft/irfft filter + oscillator bank (o-outer,
// per-osc state loaded once for the thread's 4 samples). Writes out once.
// ---------------------------------------------------------------------------
__global__ __launch_bounds__(256) void final_fused(
    const unsigned short* __restrict__ in,    // y6 [b][t][co], Tin=2048
    const short* __restrict__ wf, const float* __restrict__ bias,
    const float* __restrict__ nzf_w, const float* __restrict__ nzf_b,
    const float* __restrict__ noise,
    const float* __restrict__ amp, const float* __restrict__ frq,
    const float* __restrict__ ph, float* __restrict__ out)
{
  constexpr int STILE = 128, Tin = 2048, ROWS = STILE + 2, G = STILE / 64;
  __shared__ __align__(16) short lB[ROWS * 72];     // 18720 B
  __shared__ __align__(16) short yT[256 * 72];      // 36864 B
  __shared__ float al[1024], fqv[1024], pl[1024];   // 12288 B
  __shared__ float wl[192];

  const int b   = blockIdx.y;
  const int s0  = blockIdx.x * STILE;
  const int tid = threadIdx.x;
  const int L   = tid & 63;
  const int w   = tid >> 6;
  const int mt  = w & 1;
  const int ng  = w >> 1;

  for (int i = tid; i < 1024; i += 256) {
    al[i]  = amp[b*1024 + i];
    fqv[i] = frq[b*1024 + i];
    pl[i]  = ph[b*1024 + i];
  }
  if (tid < 192) { int o = tid >> 6, c = tid & 63; wl[c*3 + o] = nzf_w[tid]; }

  bf16x8 Af[4][4];
  {
    const short* wb = wf + (mt*32 + (L & 31))*64 + ((L >> 5) << 3);
    #pragma unroll
    for (int pd = 0; pd < 4; ++pd)
      #pragma unroll
      for (int ks = 0; ks < 4; ++ks)
        Af[pd][ks] = *(const bf16x8*)(wb + pd*4096 + ks*16);
  }

  const unsigned short* inb = in + (size_t)b * Tin * 64;
  for (int c = tid; c < ROWS*8; c += 256) {
    int row = c >> 3, pos = (c & 7) << 3;
    int g = s0 - 1 + row;
    bf16x8 v = {0,0,0,0,0,0,0,0};
    if (g >= 0 && g < Tin) v = *(const bf16x8*)(inb + (size_t)g*64 + pos);
    *(bf16x8*)&lB[row*72 + pos] = v;
  }

  f32x16 binit;
  #pragma unroll
  for (int r = 0; r < 16; ++r)
    binit[r] = bias[mt*32 + (r & 3) + 8*(r >> 2) + 4*(L >> 5)];

  __syncthreads();

  #pragma unroll
  for (int nt = 0; nt < G; ++nt) {
    int s_loc = ng*(32*G) + nt*32 + (L & 31);
    const short* bp = lB + s_loc*72 + ((L >> 5) << 3);
    f32x16 Ce = binit, Co = binit;
    #pragma unroll
    for (int ks = 0; ks < 4; ++ks) {
      bf16x8 Bm = *(const bf16x8*)(bp + ks*16);
      bf16x8 B0 = *(const bf16x8*)(bp + 72 + ks*16);
      bf16x8 Bp = *(const bf16x8*)(bp + 144 + ks*16);
      Ce = __builtin_amdgcn_mfma_f32_32x32x16_bf16(Af[0][ks], Bm, Ce, 0, 0, 0);
      Ce = __builtin_amdgcn_mfma_f32_32x32x16_bf16(Af[1][ks], B0, Ce, 0, 0, 0);
      Co = __builtin_amdgcn_mfma_f32_32x32x16_bf16(Af[2][ks], B0, Co, 0, 0, 0);
      Co = __builtin_amdgcn_mfma_f32_32x32x16_bf16(Af[3][ks], Bp, Co, 0, 0, 0);
    }
    #pragma unroll
    for (int q4 = 0; q4 < 4; ++q4) {
      int co0 = mt*32 + 8*q4 + 4*(L >> 5);
      uint2 ve, vo;
      ve.x = pack2(lrelu(Ce[4*q4+0]), lrelu(Ce[4*q4+1]));
      ve.y = pack2(lrelu(Ce[4*q4+2]), lrelu(Ce[4*q4+3]));
      vo.x = pack2(lrelu(Co[4*q4+0]), lrelu(Co[4*q4+1]));
      vo.y = pack2(lrelu(Co[4*q4+2]), lrelu(Co[4*q4+3]));
      *(uint2*)&yT[(2*s_loc)*72 + co0]     = ve;
      *(uint2*)&yT[(2*s_loc + 1)*72 + co0] = vo;
    }
  }
  __syncthreads();

  // epilogue: one thread per frame (local t = tid)
  {
    const short* yr = &yT[tid * 72];
    float c0 = nzf_b[0], c1 = nzf_b[1], c2 = nzf_b[2];
    #pragma unroll
    for (int c8 = 0; c8 < 8; ++c8) {
      bf16x8 v = *(const bf16x8*)(yr + c8*8);
      #pragma unroll
      for (int j = 0; j < 8; ++j) {
        float yv = bf2f((unsigned short)v[j]);
        int c = c8*8 + j;
        c0 = fmaf(wl[c*3+0], yv, c0);
        c1 = fmaf(wl[c*3+1], yv, c1);
        c2 = fmaf(wl[c*3+2], yv, c2);
      }
    }
    c0 *= c0; c1 *= c1; c2 *= c2;

    const int fb = 2*s0 + tid;                 // frame in [0,4096)
    const float4 n = *(const float4*)(noise + ((size_t)b*4096 + fb)*4);
    float F0  = c0 * (n.x + n.y + n.z + n.w) * 0.5f;
    float F1r = c1 * (n.x - n.z) * 0.5f;
    float F1i = -(c1 * (n.y - n.w) * 0.5f);
    float F2  = c2 * (n.x - n.y + n.z - n.w) * 0.5f;
    float r0 = 0.5f * (F0 + 2.f*F1r + F2);
    float r1 = 0.5f * (F0 - 2.f*F1i - F2);
    float r2 = 0.5f * (F0 - 2.f*F1r + F2);
    float r3 = 0.5f * (F0 + 2.f*F1i - F2);

    const int t0 = fb * 4;
    float s0a = 0.f, s1a = 0.f, s2a = 0.f, s3a = 0.f;
    if (t0 < 256) {                      // head: freq=f0, amp=a0
      const float tp = (float)(t0 + 1) * 0.5f;
      #pragma unroll 4
      for (int o = 0; o < 32; ++o) {
        float f0 = fqv[o*32], am = al[o*32];
        float hf = 0.5f * f0;
        float v0 = tp * f0, v1 = v0 + hf, v2 = v1 + hf, v3 = v2 + hf;
        s0a += am * sin_rev(v0 - floorf(v0));
        s1a += am * sin_rev(v1 - floorf(v1));
        s2a += am * sin_rev(v2 - floorf(v2));
        s3a += am * sin_rev(v3 - floorf(v3));
      }
    } else if (t0 >= 16128) {            // tail: freq=f31, amp=a31
      const float tp = (float)(t0 - 16127) * 0.5f;
      #pragma unroll 4
      for (int o = 0; o < 32; ++o) {
        float f0 = fqv[o*32 + 31], am = al[o*32 + 31], p = pl[o*32 + 31];
        float hf = 0.5f * f0;
        float v0 = p + tp * f0, v1 = v0 + hf, v2 = v1 + hf, v3 = v2 + hf;
        s0a += am * sin_rev(v0 - floorf(v0));
        s1a += am * sin_rev(v1 - floorf(v1));
        s2a += am * sin_rev(v2 - floorf(v2));
        s3a += am * sin_rev(v3 - floorf(v3));
      }
    } else {                             // middle: same interp cell for all 4
      const int i  = (t0 - 256) >> 9;
      const int m0 = (t0 - 256) & 511;
      float mm[4], fa[4], mq[4];
      #pragma unroll
      for (int js = 0; js < 4; ++js) {
        float mmv = (float)(m0 + 1 + js);
        mm[js] = mmv;
        fa[js] = ((float)(m0 + js) + 0.5f) * (1.f/512.f);
        mq[js] = mmv * mmv * (1.f/1024.f);
      }
      #pragma unroll 4
      for (int o = 0; o < 32; ++o) {
        float f0 = fqv[o*32 + i], f1 = fqv[o*32 + i + 1];
        float a0 = al[o*32 + i],  a1 = al[o*32 + i + 1];
        float p  = pl[o*32 + i];
        float df = f1 - f0, da = a1 - a0;
        #pragma unroll
        for (int js = 0; js < 4; ++js) {
          float av   = fmaf(da, fa[js], a0);
          float part = fmaf(df, mq[js], mm[js] * f0);
          float v    = fmaf(part, 0.5f, p);
          float fr   = v - floorf(v);
          float sv   = av * sin_rev(fr);
          if      (js == 0) s0a += sv;
          else if (js == 1) s1a += sv;
          else if (js == 2) s2a += sv;
          else              s3a += sv;
        }
      }
    }
    float4 res = make_float4(s0a + r0, s1a + r1, s2a + r2, s3a + r3);
    *(float4*)(out + ((size_t)b*4096 + fb)*4) = res;
  }
}

// ---------------------------------------------------------------------------
extern "C" void kernel_launch(void* const* d_in, const int* in_sizes, int n_in,
                              void* d_out, int out_size, void* d_ws, size_t ws_size,
                              hipStream_t stream) {
  (void)in_sizes; (void)n_in; (void)out_size; (void)ws_size;
  const float* x     = (const float*)d_in[0];
  const float* noise = (const float*)d_in[1];
  const float* net_w = (const float*)d_in[2];
  const float* net_b = (const float*)d_in[3];
  const float* fin_w = (const float*)d_in[4];
  const float* fin_b = (const float*)d_in[5];
  const float* amp_w = (const float*)d_in[6];
  const float* amp_b = (const float*)d_in[7];
  const float* frq_w = (const float*)d_in[8];
  const float* frq_b = (const float*)d_in[9];
  const float* nzi_w = (const float*)d_in[10];
  const float* nzi_b = (const float*)d_in[11];
  const float* nzu_w = (const float*)d_in[12];
  const float* nzu_b = (const float*)d_in[13];
  const float* nzf_w = (const float*)d_in[14];
  const float* nzf_b = (const float*)d_in[15];
  float* out = (float*)d_out;

  // workspace (~27 MiB)
  short* y5    = (short*)d_ws;                       // 64*1024*64
  short* y6    = y5 + (size_t)64*1024*64;            // 64*2048*64
  short* wfold = y6 + (size_t)64*2048*64;            // 7*16384
  float* wtF   = (float*)(wfold + 7*16384);          // 5*12288
  float* awfwT = wtF + 61440;                        // 4096
  float* nzT   = awfwT + 4096;                       // 4096
  float* ampv  = nzT + 4096;                         // 65536
  float* frqv  = ampv + 65536;
  float* phv   = frqv + 65536;

  prep_kernel<<<dim3(720), dim3(256), 0, stream>>>(
      net_w, fin_w, amp_w, frq_w, nzi_w, nzu_w, wtF, awfwT, nzT, wfold);

  z_front<<<dim3(64), dim3(1024), 0, stream>>>(
      x, wtF, net_b, fin_b, awfwT, amp_b, frq_b, nzT, nzi_b,
      wfold, nzu_b, (unsigned short*)y5, ampv, frqv, phv);

  mfma_up_t<128><<<dim3(8, 64), dim3(256), 0, stream>>>(
      (unsigned short*)y5, (unsigned short*)y6, wfold + 5*16384, nzu_b + 5*64, 1024);

  final_fused<<<dim3(16, 64), dim3(256), 0, stream>>>(
      (unsigned short*)y6, wfold + 6*16384, nzu_b + 6*64,
      nzf_w, nzf_b, noise, ampv, frqv, phv, out);
}

// Round 2
// 210.905 us; speedup vs baseline: 1.1944x; 1.1944x over previous
//
#include <hip/hip_runtime.h>
#include <math.h>

// Problem constants
//  B=64, CH=64, T_IN=32, N_OSC=32, BAND=16384, N_NOISE_FRAMES=4096, NOISE_STEP=4
//  N_UP=7, LOWEST_FREQ = 20/11025
#define LOWEST_FREQ_F 0.00181405895691609977f

typedef short bf16x8 __attribute__((ext_vector_type(8)));
typedef float f32x16 __attribute__((ext_vector_type(16)));

__device__ __forceinline__ float lrelu(float x) { return x > 0.f ? x : 0.2f * x; }
__device__ __forceinline__ float sin_rev(float fr) { return __builtin_amdgcn_sinf(fr); }
__device__ __forceinline__ float bf2f(unsigned short u) {
  union { unsigned int i; float f; } x; x.i = ((unsigned int)u) << 16; return x.f;
}
__device__ __forceinline__ unsigned short f2bf(float f) {
  union { float f; unsigned int i; } x; x.f = f;
  unsigned int r = x.i + 0x7FFFu + ((x.i >> 16) & 1u);   // RNE
  return (unsigned short)(r >> 16);
}
__device__ __forceinline__ unsigned int pack2(float a, float b) {
  return (unsigned int)f2bf(a) | ((unsigned int)f2bf(b) << 16);
}

// ---------------------------------------------------------------------------
// prep: pack frontend conv weights as float4 {w0,w1,w2,0} -> wtF4[l][ci][co],
//       amp/frq -> awfwT[c2][o][4] = (aw[2c2],fw[2c2],aw[2c2+1],fw[2c2+1]),
//       nz_init -> nzT[c][o], fold noise conv weights -> bf16
//       wfold[l][pd][co][ci]  (pd: 0=w0, 1=w1+w2, 2=w0+w1, 3=w2)
// ---------------------------------------------------------------------------
__global__ __launch_bounds__(256) void prep_kernel(
    const float* __restrict__ net_w, const float* __restrict__ fin_w,
    const float* __restrict__ amp_w, const float* __restrict__ frq_w,
    const float* __restrict__ nzi_w, const float* __restrict__ nzu_w,
    float* __restrict__ wtF4, float* __restrict__ awfwT,
    float* __restrict__ nzT, short* __restrict__ wfold)
{
  int idx = blockIdx.x * 256 + threadIdx.x;
  if (idx < 20480) {                       // wtF4: 5 layers * 4096 float4
    int l = idx >> 12, r = idx & 4095;     // r = ci*64 + co
    int ci = r >> 6, co = r & 63;
    const float* src = (l < 4) ? (net_w + l * 12288) : fin_w;
    const float* wb = src + co * 192 + ci * 3;
    float4 v = make_float4(wb[0], wb[1], wb[2], 0.f);
    ((float4*)wtF4)[idx] = v;
  } else if (idx < 24576) {                // awfwT: 4096 floats, [c2][o][4]
    int r = idx - 20480;
    int c2 = r >> 7, rem = r & 127, o = rem >> 2, k = rem & 3;
    int c = c2 * 2 + (k >> 1);
    awfwT[r] = (k & 1) ? frq_w[o * 64 + c] : amp_w[o * 64 + c];
  } else if (idx < 28672) {                // nzT: 4096
    int r = idx - 24576; int c = r >> 6, o = r & 63;
    nzT[r] = nzi_w[o * 64 + c];
  } else if (idx < 28672 + 114688) {       // wfold: 7*16384
    int r = idx - 28672;
    int l = r >> 14, q = r & 16383;
    int pd = q >> 12, co = (q >> 6) & 63, ci = q & 63;
    const float* wb = nzu_w + l * 12288 + co * 192 + ci * 3;
    float v;
    if      (pd == 0) v = wb[0];
    else if (pd == 1) v = wb[1] + wb[2];
    else if (pd == 2) v = wb[0] + wb[1];
    else              v = wb[2];
    wfold[r] = (short)f2bf(v);
  }
}

// ---------------------------------------------------------------------------
// In-LDS MFMA noise layer (even/odd folded up-conv + leaky), 8-wave version.
// tin rows = sample+1 (halos 0 and TIN+1 zero), 64 cols, stride 72 shorts.
// Ends with __syncthreads.
// v_mfma_f32_32x32x16_bf16 (HW-verified): A[m=L&31][k=(L>>5)*8+j],
// B[k][n=L&31], D col=L&31, row=(r&3)+8*(r>>2)+4*(L>>5).
// ---------------------------------------------------------------------------
template<int TIN>
__device__ __forceinline__ void noise_layer(
    const short* tin, short* tout, const short* __restrict__ wf,
    const float* __restrict__ bias, int tid)
{
  const int L  = tid & 63;
  const int w  = tid >> 6;
  const int mt = w & 1;
  const int ng = w >> 1;          // 0..3

  bf16x8 Af[4][4];
  {
    const short* wb = wf + (mt*32 + (L & 31))*64 + ((L >> 5) << 3);
    #pragma unroll
    for (int pd = 0; pd < 4; ++pd)
      #pragma unroll
      for (int ks = 0; ks < 4; ++ks)
        Af[pd][ks] = *(const bf16x8*)(wb + pd*4096 + ks*16);
  }
  f32x16 binit;
  #pragma unroll
  for (int r = 0; r < 16; ++r)
    binit[r] = bias[mt*32 + (r & 3) + 8*(r >> 2) + 4*(L >> 5)];

  if (tid < 64) { tout[tid] = 0; tout[(2*TIN + 1)*72 + tid] = 0; }

  constexpr int TOT = TIN / 32;          // n-tiles total
  constexpr int NPG = (TOT + 3) / 4;     // n-tiles per ng group
  #pragma unroll
  for (int nt = 0; nt < NPG; ++nt) {
    int ntile = ng*NPG + nt;
    if (ntile < TOT) {
      int s = ntile*32 + (L & 31);
      const short* bp = tin + s*72 + ((L >> 5) << 3);   // row s = sample s-1
      f32x16 Ce = binit, Co = binit;
      #pragma unroll
      for (int ks = 0; ks < 4; ++ks) {
        bf16x8 Bm = *(const bf16x8*)(bp + ks*16);
        bf16x8 B0 = *(const bf16x8*)(bp + 72 + ks*16);
        bf16x8 Bp = *(const bf16x8*)(bp + 144 + ks*16);
        Ce = __builtin_amdgcn_mfma_f32_32x32x16_bf16(Af[0][ks], Bm, Ce, 0, 0, 0);
        Ce = __builtin_amdgcn_mfma_f32_32x32x16_bf16(Af[1][ks], B0, Ce, 0, 0, 0);
        Co = __builtin_amdgcn_mfma_f32_32x32x16_bf16(Af[2][ks], B0, Co, 0, 0, 0);
        Co = __builtin_amdgcn_mfma_f32_32x32x16_bf16(Af[3][ks], Bp, Co, 0, 0, 0);
      }
      #pragma unroll
      for (int q4 = 0; q4 < 4; ++q4) {
        int co0 = mt*32 + 8*q4 + 4*(L >> 5);
        uint2 ve, vo;
        ve.x = pack2(lrelu(Ce[4*q4+0]), lrelu(Ce[4*q4+1]));
        ve.y = pack2(lrelu(Ce[4*q4+2]), lrelu(Ce[4*q4+3]));
        vo.x = pack2(lrelu(Co[4*q4+0]), lrelu(Co[4*q4+1]));
        vo.y = pack2(lrelu(Co[4*q4+2]), lrelu(Co[4*q4+3]));
        *(uint2*)&tout[(2*s + 1)*72 + co0] = ve;
        *(uint2*)&tout[(2*s + 2)*72 + co0] = vo;
      }
    }
  }
  __syncthreads();
}

// ---------------------------------------------------------------------------
// z_front: 512 threads/block, one block per batch.
// Conv stack: 4 waves (tid<256), 8 samples/thread, weights from GLOBAL as
// packed float4 (VMEM pipe, double-buffered in regs) -- LDS pipe only carries
// broadcast z-row reads (b128+b128+b64 per ci). FMA chain per output is
// bitwise identical to the 219us baseline. Then nz_init -> y0 (bf16 tile),
// amp/freq from global paired weights + z-transpose tile, fp64 phase
// boundaries on wave 7, noise layers 0..2 in LDS, write y3 [b][t][co].
// ---------------------------------------------------------------------------
__global__ __launch_bounds__(512) void z_front(
    const float* __restrict__ x, const float* __restrict__ wtF4,
    const float* __restrict__ net_b, const float* __restrict__ fin_b,
    const float* __restrict__ awfwT, const float* __restrict__ amp_b,
    const float* __restrict__ frq_b,
    const float* __restrict__ nzT, const float* __restrict__ nzi_b,
    const short* __restrict__ wfold, const float* __restrict__ nzu_b,
    unsigned short* __restrict__ y3, float* __restrict__ amp_o,
    float* __restrict__ frq_o, float* __restrict__ ph_o)
{
  // arena (86976 B), all regions disjoint:
  //  tileB [0,37152) | tileA [37152,55872) | za [55872,65088)
  //  zb [65088,74304) | zt [74304,82752) | fl [82752,86976)
  __shared__ __align__(16) char arena[86976];
  short* tileB = (short*)arena;
  short* tileA = (short*)(arena + 37152);
  float* za    = (float*)(arena + 55872);
  float* zb    = (float*)(arena + 65088);
  float* zt    = (float*)(arena + 74304);
  float* fl    = (float*)(arena + 82752);

  const int b   = blockIdx.x;
  const int tid = threadIdx.x;
  const int co  = tid & 63;
  const int wv  = tid >> 6;   // 0..7

  // stage input (rows shifted +1: za[c][s] = x[c][s-1]); zero halos
  for (int idx = tid; idx < 2048; idx += 512) {
    int t = idx >> 6, c = idx & 63;
    za[c*36 + t + 1] = x[b*2048 + idx];
  }
  if (tid < 64) {
    za[tid*36] = 0.f; za[tid*36 + 33] = 0.f;
    zb[tid*36] = 0.f; zb[tid*36 + 33] = 0.f;
  }
  __syncthreads();

  // ---- conv stack: 4 waves, 8 t/thread, global weights ----
  float* pa = za;
  float* pb = zb;
  for (int l = 0; l < 5; ++l) {
    if (tid < 256) {
      const int q = tid >> 6;          // 0..3, t0 = q*8
      float bv = (l < 4) ? net_b[l*64 + co] : fin_b[co];
      float acc[8];
      #pragma unroll
      for (int j = 0; j < 8; ++j) acc[j] = bv;

      const float4* wp = ((const float4*)wtF4) + l*4096 + co;  // [ci*64]
      float4 wA[4], wB[4];
      #pragma unroll
      for (int k = 0; k < 4; ++k) wA[k] = wp[k*64];

      #pragma unroll 2
      for (int cc = 0; cc < 8; ++cc) {
        // prefetch odd chunk (ci = cc*8+4..7)
        #pragma unroll
        for (int k = 0; k < 4; ++k) wB[k] = wp[(cc*8 + 4 + k)*64];
        // compute even chunk (ci = cc*8..+3)
        #pragma unroll
        for (int k = 0; k < 4; ++k) {
          const int ci = cc*8 + k;
          const float* rowp = pa + ci*36 + (q << 3);
          float4 zA = *(const float4*)(rowp);
          float4 zB = *(const float4*)(rowp + 4);
          float2 zC = *(const float2*)(rowp + 8);
          float rr[10] = {zA.x, zA.y, zA.z, zA.w, zB.x, zB.y, zB.z, zB.w,
                          zC.x, zC.y};
          float4 wgt = wA[k];
          #pragma unroll
          for (int j = 0; j < 8; ++j) {
            acc[j] = fmaf(wgt.x, rr[j],   acc[j]);
            acc[j] = fmaf(wgt.y, rr[j+1], acc[j]);
            acc[j] = fmaf(wgt.z, rr[j+2], acc[j]);
          }
        }
        // prefetch next even chunk (ci = (cc+1)*8..+3)
        if (cc < 7) {
          #pragma unroll
          for (int k = 0; k < 4; ++k) wA[k] = wp[((cc+1)*8 + k)*64];
        }
        // compute odd chunk (ci = cc*8+4..+7)
        #pragma unroll
        for (int k = 0; k < 4; ++k) {
          const int ci = cc*8 + 4 + k;
          const float* rowp = pa + ci*36 + (q << 3);
          float4 zA = *(const float4*)(rowp);
          float4 zB = *(const float4*)(rowp + 4);
          float2 zC = *(const float2*)(rowp + 8);
          float rr[10] = {zA.x, zA.y, zA.z, zA.w, zB.x, zB.y, zB.z, zB.w,
                          zC.x, zC.y};
          float4 wgt = wB[k];
          #pragma unroll
          for (int j = 0; j < 8; ++j) {
            acc[j] = fmaf(wgt.x, rr[j],   acc[j]);
            acc[j] = fmaf(wgt.y, rr[j+1], acc[j]);
            acc[j] = fmaf(wgt.z, rr[j+2], acc[j]);
          }
        }
      }

      if (l < 4) {
        #pragma unroll
        for (int j = 0; j < 8; ++j)
          pb[co*36 + (q << 3) + j + 1] = lrelu(acc[j]);
      } else {
        // final z: store UNSHIFTED (cols 0..31) + transposed copy for proj
        #pragma unroll
        for (int j = 0; j < 8; ++j) {
          int t = (q << 3) + j;
          pb[co*36 + t] = acc[j];
          zt[t*66 + co] = acc[j];
        }
      }
    }
    __syncthreads();
    float* tp = pa; pa = pb; pb = tp;
  }
  const float* zf = pa;  // final z, 64ch x 32t, cols 0..31 (no halo shift)

  // ---- y0 = nz_init 1x1 conv -> bf16 into tileA rows t+1 (global weights) --
  {
    const int q = wv;          // 0..7, t = q*4..q*4+3
    float bv0 = nzi_b[co];
    float acc[4];
    #pragma unroll
    for (int j = 0; j < 4; ++j) acc[j] = bv0;
    #pragma unroll 8
    for (int c = 0; c < 64; ++c) {
      float4 zv = *(const float4*)(zf + c*36 + (q << 2));
      float wvv = nzT[c*64 + co];
      acc[0] = fmaf(wvv, zv.x, acc[0]);
      acc[1] = fmaf(wvv, zv.y, acc[1]);
      acc[2] = fmaf(wvv, zv.z, acc[2]);
      acc[3] = fmaf(wvv, zv.w, acc[3]);
    }
    #pragma unroll
    for (int j = 0; j < 4; ++j)
      tileA[((q << 2) + j + 1)*72 + co] = (short)f2bf(acc[j]);
  }
  if (tid < 64) { tileA[tid] = 0; tileA[33*72 + tid] = 0; }

  // ---- amp / freq projections: global paired b128 weights + zt b64 reads ---
  #pragma unroll
  for (int tt = 0; tt < 2; ++tt) {
    int task = tid + 512*tt;
    int o = task & 31, t = task >> 5;
    float aa = amp_b[o], ff = frq_b[o];
    #pragma unroll 8
    for (int c2 = 0; c2 < 32; ++c2) {
      float4 w4 = ((const float4*)awfwT)[c2*32 + o];
      float2 zv = *(const float2*)(zt + t*66 + c2*2);
      aa = fmaf(w4.x, zv.x, aa); ff = fmaf(w4.y, zv.x, ff);
      aa = fmaf(w4.z, zv.y, aa); ff = fmaf(w4.w, zv.y, ff);
    }
    aa = fabsf(aa);
    float sg = 1.f / (1.f + expf(-ff));
    float fq = LOWEST_FREQ_F + sg * (1.f - LOWEST_FREQ_F);
    amp_o[b*1024 + o*32 + t] = aa;
    frq_o[b*1024 + o*32 + t] = fq;
    fl[o*33 + t] = fq;
  }
  __syncthreads();

  // ---- fp64 phase boundary prefix on wave 7 (idle in noise layers 0..1) ----
  if (wv == 7 && (tid & 63) < 32) {
    const int o = tid & 31;
    double P = 256.0 * (double)fl[o*33];
    double hd = P * 0.5;
    ph_o[b*1024 + o*32] = (float)(hd - floor(hd));
    for (int i = 1; i < 32; ++i) {
      P += 256.0 * ((double)fl[o*33 + i - 1] + (double)fl[o*33 + i]);
      hd = P * 0.5;
      ph_o[b*1024 + o*32 + i] = (float)(hd - floor(hd));
    }
  }

  // ---- noise layers 0..2 in LDS: T 32 -> 64 -> 128 -> 256 ----
  noise_layer<32> (tileA, tileB, wfold + 0*16384, nzu_b + 0*64, tid);
  noise_layer<64> (tileB, tileA, wfold + 1*16384, nzu_b + 1*64, tid);
  noise_layer<128>(tileA, tileB, wfold + 2*16384, nzu_b + 2*64, tid);

  // write y3 [b][t][co] (T=256), contiguous 16B chunks
  unsigned short* yb = y3 + (size_t)b * 16384;
  for (int c = tid; c < 2048; c += 512) {
    int row = c >> 3, pos = (c & 7) << 3;
    *(bf16x8*)(yb + c*8) = *(const bf16x8*)&tileB[(row + 1)*72 + pos];
  }
}

// ---------------------------------------------------------------------------
// Global-to-global MFMA up-conv layer, [b][t][co] layout.
// ---------------------------------------------------------------------------
template<int STILE>
__global__ __launch_bounds__(256) void mfma_up_t(
    const unsigned short* __restrict__ in, unsigned short* __restrict__ out,
    const short* __restrict__ wf, const float* __restrict__ bias, int Tin)
{
  constexpr int ROWS = STILE + 2;
  constexpr int G    = STILE / 64;   // n-tiles per wave (n-tiles total = 2G)
  __shared__ __align__(16) short lB[ROWS * 72];

  const int b   = blockIdx.y;
  const int s0  = blockIdx.x * STILE;
  const int tid = threadIdx.x;
  const int L   = tid & 63;
  const int w   = tid >> 6;
  const int mt  = w & 1;
  const int ng  = w >> 1;

  bf16x8 Af[4][4];
  {
    const short* wb = wf + (mt*32 + (L & 31))*64 + ((L >> 5) << 3);
    #pragma unroll
    for (int pd = 0; pd < 4; ++pd)
      #pragma unroll
      for (int ks = 0; ks < 4; ++ks)
        Af[pd][ks] = *(const bf16x8*)(wb + pd*4096 + ks*16);
  }

  const unsigned short* inb = in + (size_t)b * Tin * 64;
  for (int c = tid; c < ROWS*8; c += 256) {
    int row = c >> 3, pos = (c & 7) << 3;
    int g = s0 - 1 + row;
    bf16x8 v = {0,0,0,0,0,0,0,0};
    if (g >= 0 && g < Tin) v = *(const bf16x8*)(inb + (size_t)g*64 + pos);
    *(bf16x8*)&lB[row*72 + pos] = v;
  }

  f32x16 binit;
  #pragma unroll
  for (int r = 0; r < 16; ++r)
    binit[r] = bias[mt*32 + (r & 3) + 8*(r >> 2) + 4*(L >> 5)];

  __syncthreads();

  unsigned short* outb = out + (size_t)b * (2*Tin) * 64;
  #pragma unroll
  for (int nt = 0; nt < G; ++nt) {
    int s_loc = ng*(32*G) + nt*32 + (L & 31);
    const short* bp = lB + s_loc*72 + ((L >> 5) << 3);
    f32x16 Ce = binit, Co = binit;
    #pragma unroll
    for (int ks = 0; ks < 4; ++ks) {
      bf16x8 Bm = *(const bf16x8*)(bp + ks*16);
      bf16x8 B0 = *(const bf16x8*)(bp + 72 + ks*16);
      bf16x8 Bp = *(const bf16x8*)(bp + 144 + ks*16);
      Ce = __builtin_amdgcn_mfma_f32_32x32x16_bf16(Af[0][ks], Bm, Ce, 0, 0, 0);
      Ce = __builtin_amdgcn_mfma_f32_32x32x16_bf16(Af[1][ks], B0, Ce, 0, 0, 0);
      Co = __builtin_amdgcn_mfma_f32_32x32x16_bf16(Af[2][ks], B0, Co, 0, 0, 0);
      Co = __builtin_amdgcn_mfma_f32_32x32x16_bf16(Af[3][ks], Bp, Co, 0, 0, 0);
    }
    int t0 = (s0 + s_loc) * 2;
    #pragma unroll
    for (int q4 = 0; q4 < 4; ++q4) {
      int co0 = mt*32 + 8*q4 + 4*(L >> 5);
      uint2 ve, vo;
      ve.x = pack2(lrelu(Ce[4*q4+0]), lrelu(Ce[4*q4+1]));
      ve.y = pack2(lrelu(Ce[4*q4+2]), lrelu(Ce[4*q4+3]));
      vo.x = pack2(lrelu(Co[4*q4+0]), lrelu(Co[4*q4+1]));
      vo.y = pack2(lrelu(Co[4*q4+2]), lrelu(Co[4*q4+3]));
      *(uint2*)(outb + (size_t)t0*64 + co0)     = ve;
      *(uint2*)(outb + (size_t)(t0+1)*64 + co0) = vo;
    }
  }
}

// ---------------------------------------------------------------------------
// Final fused: layer 6 (Tin=2048 -> 4096, y7 stays in LDS) + nz_final coeffs
// + squared + length-4 ortho rfft/irfft filter + oscillator bank (o-outer,
// per-osc state loaded once for the thread's 4 samples). Writes out once.
// ---------------------------------------------------------------------------
__global__ __launch_bounds__(256) void final_fused(
    const unsigned short* __restrict__ in,    // y6 [b][t][co], Tin=2048
    const short* __restrict__ wf, const float* __restrict__ bias,
    const float* __restrict__ nzf_w, const float* __restrict__ nzf_b,
    const float* __restrict__ noise,
    const float* __restrict__ amp, const float* __restrict__ frq,
    const float* __restrict__ ph, float* __restrict__ out)
{
  constexpr int STILE = 128, Tin = 2048, ROWS = STILE + 2, G = STILE / 64;
  __shared__ __align__(16) short lB[ROWS * 72];     // 18720 B
  __shared__ __align__(16) short yT[256 * 72];      // 36864 B
  __shared__ float al[1024], fqv[1024], pl[1024];   // 12288 B
  __shared__ float wl[192];

  const int b   = blockIdx.y;
  const int s0  = blockIdx.x * STILE;
  const int tid = threadIdx.x;
  const int L   = tid & 63;
  const int w   = tid >> 6;
  const int mt  = w & 1;
  const int ng  = w >> 1;

  for (int i = tid; i < 1024; i += 256) {
    al[i]  = amp[b*1024 + i];
    fqv[i] = frq[b*1024 + i];
    pl[i]  = ph[b*1024 + i];
  }
  if (tid < 192) { int o = tid >> 6, c = tid & 63; wl[c*3 + o] = nzf_w[tid]; }

  bf16x8 Af[4][4];
  {
    const short* wb = wf + (mt*32 + (L & 31))*64 + ((L >> 5) << 3);
    #pragma unroll
    for (int pd = 0; pd < 4; ++pd)
      #pragma unroll
      for (int ks = 0; ks < 4; ++ks)
        Af[pd][ks] = *(const bf16x8*)(wb + pd*4096 + ks*16);
  }

  const unsigned short* inb = in + (size_t)b * Tin * 64;
  for (int c = tid; c < ROWS*8; c += 256) {
    int row = c >> 3, pos = (c & 7) << 3;
    int g = s0 - 1 + row;
    bf16x8 v = {0,0,0,0,0,0,0,0};
    if (g >= 0 && g < Tin) v = *(const bf16x8*)(inb + (size_t)g*64 + pos);
    *(bf16x8*)&lB[row*72 + pos] = v;
  }

  f32x16 binit;
  #pragma unroll
  for (int r = 0; r < 16; ++r)
    binit[r] = bias[mt*32 + (r & 3) + 8*(r >> 2) + 4*(L >> 5)];

  __syncthreads();

  #pragma unroll
  for (int nt = 0; nt < G; ++nt) {
    int s_loc = ng*(32*G) + nt*32 + (L & 31);
    const short* bp = lB + s_loc*72 + ((L >> 5) << 3);
    f32x16 Ce = binit, Co = binit;
    #pragma unroll
    for (int ks = 0; ks < 4; ++ks) {
      bf16x8 Bm = *(const bf16x8*)(bp + ks*16);
      bf16x8 B0 = *(const bf16x8*)(bp + 72 + ks*16);
      bf16x8 Bp = *(const bf16x8*)(bp + 144 + ks*16);
      Ce = __builtin_amdgcn_mfma_f32_32x32x16_bf16(Af[0][ks], Bm, Ce, 0, 0, 0);
      Ce = __builtin_amdgcn_mfma_f32_32x32x16_bf16(Af[1][ks], B0, Ce, 0, 0, 0);
      Co = __builtin_amdgcn_mfma_f32_32x32x16_bf16(Af[2][ks], B0, Co, 0, 0, 0);
      Co = __builtin_amdgcn_mfma_f32_32x32x16_bf16(Af[3][ks], Bp, Co, 0, 0, 0);
    }
    #pragma unroll
    for (int q4 = 0; q4 < 4; ++q4) {
      int co0 = mt*32 + 8*q4 + 4*(L >> 5);
      uint2 ve, vo;
      ve.x = pack2(lrelu(Ce[4*q4+0]), lrelu(Ce[4*q4+1]));
      ve.y = pack2(lrelu(Ce[4*q4+2]), lrelu(Ce[4*q4+3]));
      vo.x = pack2(lrelu(Co[4*q4+0]), lrelu(Co[4*q4+1]));
      vo.y = pack2(lrelu(Co[4*q4+2]), lrelu(Co[4*q4+3]));
      *(uint2*)&yT[(2*s_loc)*72 + co0]     = ve;
      *(uint2*)&yT[(2*s_loc + 1)*72 + co0] = vo;
    }
  }
  __syncthreads();

  // epilogue: one thread per frame (local t = tid)
  {
    const short* yr = &yT[tid * 72];
    float c0 = nzf_b[0], c1 = nzf_b[1], c2 = nzf_b[2];
    #pragma unroll
    for (int c8 = 0; c8 < 8; ++c8) {
      bf16x8 v = *(const bf16x8*)(yr + c8*8);
      #pragma unroll
      for (int j = 0; j < 8; ++j) {
        float yv = bf2f((unsigned short)v[j]);
        int c = c8*8 + j;
        c0 = fmaf(wl[c*3+0], yv, c0);
        c1 = fmaf(wl[c*3+1], yv, c1);
        c2 = fmaf(wl[c*3+2], yv, c2);
      }
    }
    c0 *= c0; c1 *= c1; c2 *= c2;

    const int fb = 2*s0 + tid;                 // frame in [0,4096)
    const float4 n = *(const float4*)(noise + ((size_t)b*4096 + fb)*4);
    float F0  = c0 * (n.x + n.y + n.z + n.w) * 0.5f;
    float F1r = c1 * (n.x - n.z) * 0.5f;
    float F1i = -(c1 * (n.y - n.w) * 0.5f);
    float F2  = c2 * (n.x - n.y + n.z - n.w) * 0.5f;
    float r0 = 0.5f * (F0 + 2.f*F1r + F2);
    float r1 = 0.5f * (F0 - 2.f*F1i - F2);
    float r2 = 0.5f * (F0 - 2.f*F1r + F2);
    float r3 = 0.5f * (F0 + 2.f*F1i - F2);

    const int t0 = fb * 4;
    float s0a = 0.f, s1a = 0.f, s2a = 0.f, s3a = 0.f;
    if (t0 < 256) {                      // head: freq=f0, amp=a0
      const float tp = (float)(t0 + 1) * 0.5f;
      #pragma unroll 4
      for (int o = 0; o < 32; ++o) {
        float f0 = fqv[o*32], am = al[o*32];
        float hf = 0.5f * f0;
        float v0 = tp * f0, v1 = v0 + hf, v2 = v1 + hf, v3 = v2 + hf;
        s0a += am * sin_rev(v0 - floorf(v0));
        s1a += am * sin_rev(v1 - floorf(v1));
        s2a += am * sin_rev(v2 - floorf(v2));
        s3a += am * sin_rev(v3 - floorf(v3));
      }
    } else if (t0 >= 16128) {            // tail: freq=f31, amp=a31
      const float tp = (float)(t0 - 16127) * 0.5f;
      #pragma unroll 4
      for (int o = 0; o < 32; ++o) {
        float f0 = fqv[o*32 + 31], am = al[o*32 + 31], p = pl[o*32 + 31];
        float hf = 0.5f * f0;
        float v0 = p + tp * f0, v1 = v0 + hf, v2 = v1 + hf, v3 = v2 + hf;
        s0a += am * sin_rev(v0 - floorf(v0));
        s1a += am * sin_rev(v1 - floorf(v1));
        s2a += am * sin_rev(v2 - floorf(v2));
        s3a += am * sin_rev(v3 - floorf(v3));
      }
    } else {                             // middle: same interp cell for all 4
      const int i  = (t0 - 256) >> 9;
      const int m0 = (t0 - 256) & 511;
      float mm[4], fa[4], mq[4];
      #pragma unroll
      for (int js = 0; js < 4; ++js) {
        float mmv = (float)(m0 + 1 + js);
        mm[js] = mmv;
        fa[js] = ((float)(m0 + js) + 0.5f) * (1.f/512.f);
        mq[js] = mmv * mmv * (1.f/1024.f);
      }
      #pragma unroll 4
      for (int o = 0; o < 32; ++o) {
        float f0 = fqv[o*32 + i], f1 = fqv[o*32 + i + 1];
        float a0 = al[o*32 + i],  a1 = al[o*32 + i + 1];
        float p  = pl[o*32 + i];
        float df = f1 - f0, da = a1 - a0;
        #pragma unroll
        for (int js = 0; js < 4; ++js) {
          float av   = fmaf(da, fa[js], a0);
          float part = fmaf(df, mq[js], mm[js] * f0);
          float v    = fmaf(part, 0.5f, p);
          float fr   = v - floorf(v);
          float sv   = av * sin_rev(fr);
          if      (js == 0) s0a += sv;
          else if (js == 1) s1a += sv;
          else if (js == 2) s2a += sv;
          else              s3a += sv;
        }
      }
    }
    float4 res = make_float4(s0a + r0, s1a + r1, s2a + r2, s3a + r3);
    *(float4*)(out + ((size_t)b*4096 + fb)*4) = res;
  }
}

// ---------------------------------------------------------------------------
extern "C" void kernel_launch(void* const* d_in, const int* in_sizes, int n_in,
                              void* d_out, int out_size, void* d_ws, size_t ws_size,
                              hipStream_t stream) {
  (void)in_sizes; (void)n_in; (void)out_size; (void)ws_size;
  const float* x     = (const float*)d_in[0];
  const float* noise = (const float*)d_in[1];
  const float* net_w = (const float*)d_in[2];
  const float* net_b = (const float*)d_in[3];
  const float* fin_w = (const float*)d_in[4];
  const float* fin_b = (const float*)d_in[5];
  const float* amp_w = (const float*)d_in[6];
  const float* amp_b = (const float*)d_in[7];
  const float* frq_w = (const float*)d_in[8];
  const float* frq_b = (const float*)d_in[9];
  const float* nzi_w = (const float*)d_in[10];
  const float* nzi_b = (const float*)d_in[11];
  const float* nzu_w = (const float*)d_in[12];
  const float* nzu_b = (const float*)d_in[13];
  const float* nzf_w = (const float*)d_in[14];
  const float* nzf_b = (const float*)d_in[15];
  float* out = (float*)d_out;

  // workspace (~32 MiB)
  short* y3    = (short*)d_ws;                       // 64*256*64
  short* y4    = y3 + (size_t)64*256*64;             // 64*512*64
  short* y5    = y4 + (size_t)64*512*64;             // 64*1024*64
  short* y6    = y5 + (size_t)64*1024*64;            // 64*2048*64
  short* wfold = y6 + (size_t)64*2048*64;            // 7*16384
  float* wtF4  = (float*)(wfold + 7*16384);          // 5*4096*4 = 81920
  float* awfwT = wtF4 + 81920;                       // 4096
  float* nzT   = awfwT + 4096;                       // 4096
  float* ampv  = nzT + 4096;                         // 65536
  float* frqv  = ampv + 65536;
  float* phv   = frqv + 65536;

  prep_kernel<<<dim3(560), dim3(256), 0, stream>>>(
      net_w, fin_w, amp_w, frq_w, nzi_w, nzu_w, wtF4, awfwT, nzT, wfold);

  z_front<<<dim3(64), dim3(512), 0, stream>>>(
      x, wtF4, net_b, fin_b, awfwT, amp_b, frq_b, nzT, nzi_b,
      wfold, nzu_b, (unsigned short*)y3, ampv, frqv, phv);

  mfma_up_t<64> <<<dim3(4, 64), dim3(256), 0, stream>>>(
      (unsigned short*)y3, (unsigned short*)y4, wfold + 3*16384, nzu_b + 3*64, 256);
  mfma_up_t<128><<<dim3(4, 64), dim3(256), 0, stream>>>(
      (unsigned short*)y4, (unsigned short*)y5, wfold + 4*16384, nzu_b + 4*64, 512);
  mfma_up_t<128><<<dim3(8, 64), dim3(256), 0, stream>>>(
      (unsigned short*)y5, (unsigned short*)y6, wfold + 5*16384, nzu_b + 5*64, 1024);

  final_fused<<<dim3(16, 64), dim3(256), 0, stream>>>(
      (unsigned short*)y6, wfold + 6*16384, nzu_b + 6*64,
      nzf_w, nzf_b, noise, ampv, frqv, phv, out);
}

// Round 3
// 204.680 us; speedup vs baseline: 1.2308x; 1.0304x over previous
//
#include <hip/hip_runtime.h>
#include <math.h>

// Problem constants
//  B=64, CH=64, T_IN=32, N_OSC=32, BAND=16384, N_NOISE_FRAMES=4096, NOISE_STEP=4
//  N_UP=7, LOWEST_FREQ = 20/11025
#define LOWEST_FREQ_F 0.00181405895691609977f

typedef short bf16x8 __attribute__((ext_vector_type(8)));
typedef float f32x16 __attribute__((ext_vector_type(16)));

__device__ __forceinline__ float lrelu(float x) { return x > 0.f ? x : 0.2f * x; }
__device__ __forceinline__ float sin_rev(float fr) { return __builtin_amdgcn_sinf(fr); }
__device__ __forceinline__ float bf2f(unsigned short u) {
  union { unsigned int i; float f; } x; x.i = ((unsigned int)u) << 16; return x.f;
}
__device__ __forceinline__ unsigned short f2bf(float f) {
  union { float f; unsigned int i; } x; x.f = f;
  unsigned int r = x.i + 0x7FFFu + ((x.i >> 16) & 1u);   // RNE
  return (unsigned short)(r >> 16);
}
__device__ __forceinline__ unsigned int pack2(float a, float b) {
  return (unsigned int)f2bf(a) | ((unsigned int)f2bf(b) << 16);
}

// ---------------------------------------------------------------------------
// prep: pack frontend conv weights as float4 {w0,w1,w2,0} -> wtF4[l][ci][co],
//       amp/frq -> awfwT[c2][o][4] = (aw[2c2],fw[2c2],aw[2c2+1],fw[2c2+1]),
//       nz_init -> nzT[c][o], fold noise conv weights -> bf16
//       wfold[l][pd][co][ci]  (pd: 0=w0, 1=w1+w2, 2=w0+w1, 3=w2)
// ---------------------------------------------------------------------------
__global__ __launch_bounds__(256) void prep_kernel(
    const float* __restrict__ net_w, const float* __restrict__ fin_w,
    const float* __restrict__ amp_w, const float* __restrict__ frq_w,
    const float* __restrict__ nzi_w, const float* __restrict__ nzu_w,
    float* __restrict__ wtF4, float* __restrict__ awfwT,
    float* __restrict__ nzT, short* __restrict__ wfold)
{
  int idx = blockIdx.x * 256 + threadIdx.x;
  if (idx < 20480) {                       // wtF4: 5 layers * 4096 float4
    int l = idx >> 12, r = idx & 4095;     // r = ci*64 + co
    int ci = r >> 6, co = r & 63;
    const float* src = (l < 4) ? (net_w + l * 12288) : fin_w;
    const float* wb = src + co * 192 + ci * 3;
    float4 v = make_float4(wb[0], wb[1], wb[2], 0.f);
    ((float4*)wtF4)[idx] = v;
  } else if (idx < 24576) {                // awfwT: 4096 floats, [c2][o][4]
    int r = idx - 20480;
    int c2 = r >> 7, rem = r & 127, o = rem >> 2, k = rem & 3;
    int c = c2 * 2 + (k >> 1);
    awfwT[r] = (k & 1) ? frq_w[o * 64 + c] : amp_w[o * 64 + c];
  } else if (idx < 28672) {                // nzT: 4096
    int r = idx - 24576; int c = r >> 6, o = r & 63;
    nzT[r] = nzi_w[o * 64 + c];
  } else if (idx < 28672 + 114688) {       // wfold: 7*16384
    int r = idx - 28672;
    int l = r >> 14, q = r & 16383;
    int pd = q >> 12, co = (q >> 6) & 63, ci = q & 63;
    const float* wb = nzu_w + l * 12288 + co * 192 + ci * 3;
    float v;
    if      (pd == 0) v = wb[0];
    else if (pd == 1) v = wb[1] + wb[2];
    else if (pd == 2) v = wb[0] + wb[1];
    else              v = wb[2];
    wfold[r] = (short)f2bf(v);
  }
}

// ---------------------------------------------------------------------------
// In-LDS MFMA noise layer (even/odd folded up-conv + leaky), 8-wave version.
// tin rows = sample+1 (halos 0 and TIN+1 zero), 64 cols, stride 72 shorts.
// Ends with __syncthreads.
// v_mfma_f32_32x32x16_bf16 (HW-verified): A[m=L&31][k=(L>>5)*8+j],
// B[k][n=L&31], D col=L&31, row=(r&3)+8*(r>>2)+4*(L>>5).
// ---------------------------------------------------------------------------
template<int TIN>
__device__ __forceinline__ void noise_layer(
    const short* tin, short* tout, const short* __restrict__ wf,
    const float* __restrict__ bias, int tid)
{
  const int L  = tid & 63;
  const int w  = tid >> 6;
  const int mt = w & 1;
  const int ng = w >> 1;          // 0..3

  bf16x8 Af[4][4];
  {
    const short* wb = wf + (mt*32 + (L & 31))*64 + ((L >> 5) << 3);
    #pragma unroll
    for (int pd = 0; pd < 4; ++pd)
      #pragma unroll
      for (int ks = 0; ks < 4; ++ks)
        Af[pd][ks] = *(const bf16x8*)(wb + pd*4096 + ks*16);
  }
  f32x16 binit;
  #pragma unroll
  for (int r = 0; r < 16; ++r)
    binit[r] = bias[mt*32 + (r & 3) + 8*(r >> 2) + 4*(L >> 5)];

  if (tid < 64) { tout[tid] = 0; tout[(2*TIN + 1)*72 + tid] = 0; }

  constexpr int TOT = TIN / 32;          // n-tiles total
  constexpr int NPG = (TOT + 3) / 4;     // n-tiles per ng group
  #pragma unroll
  for (int nt = 0; nt < NPG; ++nt) {
    int ntile = ng*NPG + nt;
    if (ntile < TOT) {
      int s = ntile*32 + (L & 31);
      const short* bp = tin + s*72 + ((L >> 5) << 3);   // row s = sample s-1
      f32x16 Ce = binit, Co = binit;
      #pragma unroll
      for (int ks = 0; ks < 4; ++ks) {
        bf16x8 Bm = *(const bf16x8*)(bp + ks*16);
        bf16x8 B0 = *(const bf16x8*)(bp + 72 + ks*16);
        bf16x8 Bp = *(const bf16x8*)(bp + 144 + ks*16);
        Ce = __builtin_amdgcn_mfma_f32_32x32x16_bf16(Af[0][ks], Bm, Ce, 0, 0, 0);
        Ce = __builtin_amdgcn_mfma_f32_32x32x16_bf16(Af[1][ks], B0, Ce, 0, 0, 0);
        Co = __builtin_amdgcn_mfma_f32_32x32x16_bf16(Af[2][ks], B0, Co, 0, 0, 0);
        Co = __builtin_amdgcn_mfma_f32_32x32x16_bf16(Af[3][ks], Bp, Co, 0, 0, 0);
      }
      #pragma unroll
      for (int q4 = 0; q4 < 4; ++q4) {
        int co0 = mt*32 + 8*q4 + 4*(L >> 5);
        uint2 ve, vo;
        ve.x = pack2(lrelu(Ce[4*q4+0]), lrelu(Ce[4*q4+1]));
        ve.y = pack2(lrelu(Ce[4*q4+2]), lrelu(Ce[4*q4+3]));
        vo.x = pack2(lrelu(Co[4*q4+0]), lrelu(Co[4*q4+1]));
        vo.y = pack2(lrelu(Co[4*q4+2]), lrelu(Co[4*q4+3]));
        *(uint2*)&tout[(2*s + 1)*72 + co0] = ve;
        *(uint2*)&tout[(2*s + 2)*72 + co0] = vo;
      }
    }
  }
  __syncthreads();
}

// ---------------------------------------------------------------------------
// Generic in-LDS up-conv stage for the fused up345 kernel.
// bin row r = input sample (ibase + r); processes NT n-tiles of 32 output
// pairs; pair sl reads bin rows sl+ROFF .. sl+ROFF+2; writes output samples
// to rows 2sl, 2sl+1 of bout (or gout rows, [t][64] layout, if TOGLOBAL).
// 256 threads = 2 wave-pairs; tile n handled by wave-pair (n & 1).
// ---------------------------------------------------------------------------
template<int NT, int ROFF, bool TOGLOBAL>
__device__ __forceinline__ void up_stage(
    const short* bin, short* bout, unsigned short* gout,
    const short* __restrict__ wf, const float* __restrict__ bias, int tid)
{
  const int L  = tid & 63;
  const int w  = tid >> 6;
  const int mt = w & 1;
  const int pg = w >> 1;   // 0..1

  bf16x8 Af[4][4];
  {
    const short* wb = wf + (mt*32 + (L & 31))*64 + ((L >> 5) << 3);
    #pragma unroll
    for (int pd = 0; pd < 4; ++pd)
      #pragma unroll
      for (int ks = 0; ks < 4; ++ks)
        Af[pd][ks] = *(const bf16x8*)(wb + pd*4096 + ks*16);
  }
  f32x16 binit;
  #pragma unroll
  for (int r = 0; r < 16; ++r)
    binit[r] = bias[mt*32 + (r & 3) + 8*(r >> 2) + 4*(L >> 5)];

  for (int n = pg; n < NT; n += 2) {
    int sl = n*32 + (L & 31);
    const short* bp = bin + (sl + ROFF)*72 + ((L >> 5) << 3);
    f32x16 Ce = binit, Co = binit;
    #pragma unroll
    for (int ks = 0; ks < 4; ++ks) {
      bf16x8 Bm = *(const bf16x8*)(bp + ks*16);
      bf16x8 B0 = *(const bf16x8*)(bp + 72 + ks*16);
      bf16x8 Bp = *(const bf16x8*)(bp + 144 + ks*16);
      Ce = __builtin_amdgcn_mfma_f32_32x32x16_bf16(Af[0][ks], Bm, Ce, 0, 0, 0);
      Ce = __builtin_amdgcn_mfma_f32_32x32x16_bf16(Af[1][ks], B0, Ce, 0, 0, 0);
      Co = __builtin_amdgcn_mfma_f32_32x32x16_bf16(Af[2][ks], B0, Co, 0, 0, 0);
      Co = __builtin_amdgcn_mfma_f32_32x32x16_bf16(Af[3][ks], Bp, Co, 0, 0, 0);
    }
    #pragma unroll
    for (int q4 = 0; q4 < 4; ++q4) {
      int co0 = mt*32 + 8*q4 + 4*(L >> 5);
      uint2 ve, vo;
      ve.x = pack2(lrelu(Ce[4*q4+0]), lrelu(Ce[4*q4+1]));
      ve.y = pack2(lrelu(Ce[4*q4+2]), lrelu(Ce[4*q4+3]));
      vo.x = pack2(lrelu(Co[4*q4+0]), lrelu(Co[4*q4+1]));
      vo.y = pack2(lrelu(Co[4*q4+2]), lrelu(Co[4*q4+3]));
      if (TOGLOBAL) {
        *(uint2*)(gout + (size_t)(2*sl)*64 + co0)     = ve;
        *(uint2*)(gout + (size_t)(2*sl + 1)*64 + co0) = vo;
      } else {
        *(uint2*)&bout[(2*sl)*72 + co0]     = ve;
        *(uint2*)&bout[(2*sl + 1)*72 + co0] = vo;
      }
    }
  }
}

// ---------------------------------------------------------------------------
// up345: fused noise layers 3,4,5 (y3 T=256 -> y6 T=2048) entirely in LDS.
// Block (bx, b), bx in [0,8): produces y6 samples [256bx, 256bx+256).
// Halo recompute chain (all ranges verified exact):
//   s3: y3 samples [32bx-2, 32bx+64)   (66 rows, OOB zeroed at load)
//   L3: pairs [32bx-1, 32bx+63)  -> s4 y4 samples [64bx-2, 64bx+126)  (128 r)
//   L4: pairs [64bx-1, 64bx+95)  -> s5 y5 samples [128bx-2, 128bx+190) (192 r)
//   L5: pairs [128bx, 128bx+128) -> y6 global [256bx, 256bx+256)
// Between stages, rows whose sample index is outside the true layer length
// (only possible at bx==0 low / bx==7 high) are re-zeroed so halo semantics
// match the unfused mfma_up_t chain exactly.
// ---------------------------------------------------------------------------
__global__ __launch_bounds__(256) void up345(
    const unsigned short* __restrict__ y3, unsigned short* __restrict__ y6,
    const short* __restrict__ wfold, const float* __restrict__ nzu_b)
{
  __shared__ __align__(16) short s3[66*72];    //  9504 B
  __shared__ __align__(16) short s4[128*72];   // 18432 B
  __shared__ __align__(16) short s5[192*72];   // 27648 B

  const int b   = blockIdx.y;
  const int bx  = blockIdx.x;    // 0..7
  const int tid = threadIdx.x;

  // stage y3 tile: row r <- sample 32bx-2+r (zero OOB)
  const unsigned short* inb = y3 + (size_t)b * 256 * 64;
  for (int c = tid; c < 66*8; c += 256) {
    int row = c >> 3, pos = (c & 7) << 3;
    int g = 32*bx - 2 + row;
    bf16x8 v = {0,0,0,0,0,0,0,0};
    if (g >= 0 && g < 256) v = *(const bf16x8*)(inb + (size_t)g*64 + pos);
    *(bf16x8*)&s3[row*72 + pos] = v;
  }
  __syncthreads();

  up_stage<2,0,false>(s3, s4, nullptr, wfold + 3*16384, nzu_b + 3*64, tid);
  __syncthreads();
  // re-zero s4 rows with sample outside [0,512): bx==0 rows 0,1; bx==7 r>=66
  if (bx == 0) {
    if (tid < 128) s4[(tid >> 6)*72 + (tid & 63)] = 0;
  } else if (bx == 7) {
    for (int i = tid; i < 62*64; i += 256) {
      int r = 66 + (i >> 6);
      s4[r*72 + (i & 63)] = 0;
    }
  }
  __syncthreads();

  up_stage<3,0,false>(s4, s5, nullptr, wfold + 4*16384, nzu_b + 4*64, tid);
  __syncthreads();
  // re-zero s5 rows with sample outside [0,1024): bx==0 rows 0,1; bx==7 r>=130
  if (bx == 0) {
    if (tid < 128) s5[(tid >> 6)*72 + (tid & 63)] = 0;
  } else if (bx == 7) {
    for (int i = tid; i < 62*64; i += 256) {
      int r = 130 + (i >> 6);
      s5[r*72 + (i & 63)] = 0;
    }
  }
  __syncthreads();

  unsigned short* outb = y6 + ((size_t)b*2048 + 256*bx) * 64;
  up_stage<4,1,true>(s5, nullptr, outb, wfold + 5*16384, nzu_b + 5*64, tid);
}

// ---------------------------------------------------------------------------
// z_front: 512 threads/block, one block per batch.
// Conv stack: ALL 8 waves, 4 samples/thread, weights from GLOBAL as packed
// float4 with full-chunk (8 ci) register double-buffer -- prefetch distance
// ~2x L2 latency, 2 conv waves/SIMD for latency hiding. LDS carries only
// wave-uniform broadcast z-row reads. FMA chain per (co,t) is bitwise
// identical to the previous version. Then nz_init -> y0 (bf16 tile),
// amp/freq from global paired weights + z-transpose tile, fp64 phase
// boundaries on wave 7, noise layers 0..2 in LDS, write y3 [b][t][co].
// ---------------------------------------------------------------------------
__global__ __launch_bounds__(512) void z_front(
    const float* __restrict__ x, const float* __restrict__ wtF4,
    const float* __restrict__ net_b, const float* __restrict__ fin_b,
    const float* __restrict__ awfwT, const float* __restrict__ amp_b,
    const float* __restrict__ frq_b,
    const float* __restrict__ nzT, const float* __restrict__ nzi_b,
    const short* __restrict__ wfold, const float* __restrict__ nzu_b,
    unsigned short* __restrict__ y3, float* __restrict__ amp_o,
    float* __restrict__ frq_o, float* __restrict__ ph_o)
{
  // arena (86976 B), all regions disjoint:
  //  tileB [0,37152) | tileA [37152,55872) | za [55872,65088)
  //  zb [65088,74304) | zt [74304,82752) | fl [82752,86976)
  __shared__ __align__(16) char arena[86976];
  short* tileB = (short*)arena;
  short* tileA = (short*)(arena + 37152);
  float* za    = (float*)(arena + 55872);
  float* zb    = (float*)(arena + 65088);
  float* zt    = (float*)(arena + 74304);
  float* fl    = (float*)(arena + 82752);

  const int b   = blockIdx.x;
  const int tid = threadIdx.x;
  const int co  = tid & 63;
  const int wv  = tid >> 6;   // 0..7

  // stage input (rows shifted +1: za[c][s] = x[c][s-1]); zero halos
  for (int idx = tid; idx < 2048; idx += 512) {
    int t = idx >> 6, c = idx & 63;
    za[c*36 + t + 1] = x[b*2048 + idx];
  }
  if (tid < 64) {
    za[tid*36] = 0.f; za[tid*36 + 33] = 0.f;
    zb[tid*36] = 0.f; zb[tid*36 + 33] = 0.f;
  }
  __syncthreads();

  // ---- conv stack: 8 waves, 4 t/thread, global weights (8-ci prefetch) ----
  float* pa = za;
  float* pb = zb;
  for (int l = 0; l < 5; ++l) {
    {
      const int t0 = wv << 2;
      float bv = (l < 4) ? net_b[l*64 + co] : fin_b[co];
      float acc[4];
      #pragma unroll
      for (int j = 0; j < 4; ++j) acc[j] = bv;

      const float4* wp = ((const float4*)wtF4) + l*4096 + co;  // [ci*64]
      float4 wCur[8], wNxt[8];
      #pragma unroll
      for (int k = 0; k < 8; ++k) wCur[k] = wp[k*64];

      for (int cc = 0; cc < 8; ++cc) {
        if (cc < 7) {
          #pragma unroll
          for (int k = 0; k < 8; ++k) wNxt[k] = wp[((cc+1)*8 + k)*64];
        }
        #pragma unroll
        for (int k = 0; k < 8; ++k) {
          const int ci = cc*8 + k;
          const float* rowp = pa + ci*36 + t0;
          float4 zA = *(const float4*)(rowp);
          float2 zB = *(const float2*)(rowp + 4);
          float rr[6] = {zA.x, zA.y, zA.z, zA.w, zB.x, zB.y};
          float4 wgt = wCur[k];
          #pragma unroll
          for (int j = 0; j < 4; ++j) {
            acc[j] = fmaf(wgt.x, rr[j],   acc[j]);
            acc[j] = fmaf(wgt.y, rr[j+1], acc[j]);
            acc[j] = fmaf(wgt.z, rr[j+2], acc[j]);
          }
        }
        if (cc < 7) {
          #pragma unroll
          for (int k = 0; k < 8; ++k) wCur[k] = wNxt[k];
        }
      }

      if (l < 4) {
        #pragma unroll
        for (int j = 0; j < 4; ++j)
          pb[co*36 + t0 + j + 1] = lrelu(acc[j]);
      } else {
        // final z: store UNSHIFTED (cols 0..31) + transposed copy for proj
        #pragma unroll
        for (int j = 0; j < 4; ++j) {
          int t = t0 + j;
          pb[co*36 + t] = acc[j];
          zt[t*66 + co] = acc[j];
        }
      }
    }
    __syncthreads();
    float* tp = pa; pa = pb; pb = tp;
  }
  const float* zf = pa;  // final z, 64ch x 32t, cols 0..31 (no halo shift)

  // ---- y0 = nz_init 1x1 conv -> bf16 into tileA rows t+1 (global weights) --
  {
    const int q = wv;          // 0..7, t = q*4..q*4+3
    float bv0 = nzi_b[co];
    float acc[4];
    #pragma unroll
    for (int j = 0; j < 4; ++j) acc[j] = bv0;
    #pragma unroll 8
    for (int c = 0; c < 64; ++c) {
      float4 zv = *(const float4*)(zf + c*36 + (q << 2));
      float wvv = nzT[c*64 + co];
      acc[0] = fmaf(wvv, zv.x, acc[0]);
      acc[1] = fmaf(wvv, zv.y, acc[1]);
      acc[2] = fmaf(wvv, zv.z, acc[2]);
      acc[3] = fmaf(wvv, zv.w, acc[3]);
    }
    #pragma unroll
    for (int j = 0; j < 4; ++j)
      tileA[((q << 2) + j + 1)*72 + co] = (short)f2bf(acc[j]);
  }
  if (tid < 64) { tileA[tid] = 0; tileA[33*72 + tid] = 0; }

  // ---- amp / freq projections: global paired b128 weights + zt b64 reads ---
  #pragma unroll
  for (int tt = 0; tt < 2; ++tt) {
    int task = tid + 512*tt;
    int o = task & 31, t = task >> 5;
    float aa = amp_b[o], ff = frq_b[o];
    #pragma unroll 8
    for (int c2 = 0; c2 < 32; ++c2) {
      float4 w4 = ((const float4*)awfwT)[c2*32 + o];
      float2 zv = *(const float2*)(zt + t*66 + c2*2);
      aa = fmaf(w4.x, zv.x, aa); ff = fmaf(w4.y, zv.x, ff);
      aa = fmaf(w4.z, zv.y, aa); ff = fmaf(w4.w, zv.y, ff);
    }
    aa = fabsf(aa);
    float sg = 1.f / (1.f + expf(-ff));
    float fq = LOWEST_FREQ_F + sg * (1.f - LOWEST_FREQ_F);
    amp_o[b*1024 + o*32 + t] = aa;
    frq_o[b*1024 + o*32 + t] = fq;
    fl[o*33 + t] = fq;
  }
  __syncthreads();

  // ---- fp64 phase boundary prefix on wave 7 (idle in noise layers 0..1) ----
  if (wv == 7 && (tid & 63) < 32) {
    const int o = tid & 31;
    double P = 256.0 * (double)fl[o*33];
    double hd = P * 0.5;
    ph_o[b*1024 + o*32] = (float)(hd - floor(hd));
    for (int i = 1; i < 32; ++i) {
      P += 256.0 * ((double)fl[o*33 + i - 1] + (double)fl[o*33 + i]);
      hd = P * 0.5;
      ph_o[b*1024 + o*32 + i] = (float)(hd - floor(hd));
    }
  }

  // ---- noise layers 0..2 in LDS: T 32 -> 64 -> 128 -> 256 ----
  noise_layer<32> (tileA, tileB, wfold + 0*16384, nzu_b + 0*64, tid);
  noise_layer<64> (tileB, tileA, wfold + 1*16384, nzu_b + 1*64, tid);
  noise_layer<128>(tileA, tileB, wfold + 2*16384, nzu_b + 2*64, tid);

  // write y3 [b][t][co] (T=256), contiguous 16B chunks
  unsigned short* yb = y3 + (size_t)b * 16384;
  for (int c = tid; c < 2048; c += 512) {
    int row = c >> 3, pos = (c & 7) << 3;
    *(bf16x8*)(yb + c*8) = *(const bf16x8*)&tileB[(row + 1)*72 + pos];
  }
}

// ---------------------------------------------------------------------------
// Final fused: layer 6 (Tin=2048 -> 4096, y7 stays in LDS) + nz_final coeffs
// + squared + length-4 ortho rfft/irfft filter + oscillator bank (o-outer,
// per-osc state loaded once for the thread's 4 samples). Writes out once.
// ---------------------------------------------------------------------------
__global__ __launch_bounds__(256) void final_fused(
    const unsigned short* __restrict__ in,    // y6 [b][t][co], Tin=2048
    const short* __restrict__ wf, const float* __restrict__ bias,
    const float* __restrict__ nzf_w, const float* __restrict__ nzf_b,
    const float* __restrict__ noise,
    const float* __restrict__ amp, const float* __restrict__ frq,
    const float* __restrict__ ph, float* __restrict__ out)
{
  constexpr int STILE = 128, Tin = 2048, ROWS = STILE + 2, G = STILE / 64;
  __shared__ __align__(16) short lB[ROWS * 72];     // 18720 B
  __shared__ __align__(16) short yT[256 * 72];      // 36864 B
  __shared__ float al[1024], fqv[1024], pl[1024];   // 12288 B
  __shared__ float wl[192];

  const int b   = blockIdx.y;
  const int s0  = blockIdx.x * STILE;
  const int tid = threadIdx.x;
  const int L   = tid & 63;
  const int w   = tid >> 6;
  const int mt  = w & 1;
  const int ng  = w >> 1;

  for (int i = tid; i < 1024; i += 256) {
    al[i]  = amp[b*1024 + i];
    fqv[i] = frq[b*1024 + i];
    pl[i]  = ph[b*1024 + i];
  }
  if (tid < 192) { int o = tid >> 6, c = tid & 63; wl[c*3 + o] = nzf_w[tid]; }

  bf16x8 Af[4][4];
  {
    const short* wb = wf + (mt*32 + (L & 31))*64 + ((L >> 5) << 3);
    #pragma unroll
    for (int pd = 0; pd < 4; ++pd)
      #pragma unroll
      for (int ks = 0; ks < 4; ++ks)
        Af[pd][ks] = *(const bf16x8*)(wb + pd*4096 + ks*16);
  }

  const unsigned short* inb = in + (size_t)b * Tin * 64;
  for (int c = tid; c < ROWS*8; c += 256) {
    int row = c >> 3, pos = (c & 7) << 3;
    int g = s0 - 1 + row;
    bf16x8 v = {0,0,0,0,0,0,0,0};
    if (g >= 0 && g < Tin) v = *(const bf16x8*)(inb + (size_t)g*64 + pos);
    *(bf16x8*)&lB[row*72 + pos] = v;
  }

  f32x16 binit;
  #pragma unroll
  for (int r = 0; r < 16; ++r)
    binit[r] = bias[mt*32 + (r & 3) + 8*(r >> 2) + 4*(L >> 5)];

  __syncthreads();

  #pragma unroll
  for (int nt = 0; nt < G; ++nt) {
    int s_loc = ng*(32*G) + nt*32 + (L & 31);
    const short* bp = lB + s_loc*72 + ((L >> 5) << 3);
    f32x16 Ce = binit, Co = binit;
    #pragma unroll
    for (int ks = 0; ks < 4; ++ks) {
      bf16x8 Bm = *(const bf16x8*)(bp + ks*16);
      bf16x8 B0 = *(const bf16x8*)(bp + 72 + ks*16);
      bf16x8 Bp = *(const bf16x8*)(bp + 144 + ks*16);
      Ce = __builtin_amdgcn_mfma_f32_32x32x16_bf16(Af[0][ks], Bm, Ce, 0, 0, 0);
      Ce = __builtin_amdgcn_mfma_f32_32x32x16_bf16(Af[1][ks], B0, Ce, 0, 0, 0);
      Co = __builtin_amdgcn_mfma_f32_32x32x16_bf16(Af[2][ks], B0, Co, 0, 0, 0);
      Co = __builtin_amdgcn_mfma_f32_32x32x16_bf16(Af[3][ks], Bp, Co, 0, 0, 0);
    }
    #pragma unroll
    for (int q4 = 0; q4 < 4; ++q4) {
      int co0 = mt*32 + 8*q4 + 4*(L >> 5);
      uint2 ve, vo;
      ve.x = pack2(lrelu(Ce[4*q4+0]), lrelu(Ce[4*q4+1]));
      ve.y = pack2(lrelu(Ce[4*q4+2]), lrelu(Ce[4*q4+3]));
      vo.x = pack2(lrelu(Co[4*q4+0]), lrelu(Co[4*q4+1]));
      vo.y = pack2(lrelu(Co[4*q4+2]), lrelu(Co[4*q4+3]));
      *(uint2*)&yT[(2*s_loc)*72 + co0]     = ve;
      *(uint2*)&yT[(2*s_loc + 1)*72 + co0] = vo;
    }
  }
  __syncthreads();

  // epilogue: one thread per frame (local t = tid)
  {
    const short* yr = &yT[tid * 72];
    float c0 = nzf_b[0], c1 = nzf_b[1], c2 = nzf_b[2];
    #pragma unroll
    for (int c8 = 0; c8 < 8; ++c8) {
      bf16x8 v = *(const bf16x8*)(yr + c8*8);
      #pragma unroll
      for (int j = 0; j < 8; ++j) {
        float yv = bf2f((unsigned short)v[j]);
        int c = c8*8 + j;
        c0 = fmaf(wl[c*3+0], yv, c0);
        c1 = fmaf(wl[c*3+1], yv, c1);
        c2 = fmaf(wl[c*3+2], yv, c2);
      }
    }
    c0 *= c0; c1 *= c1; c2 *= c2;

    const int fb = 2*s0 + tid;                 // frame in [0,4096)
    const float4 n = *(const float4*)(noise + ((size_t)b*4096 + fb)*4);
    float F0  = c0 * (n.x + n.y + n.z + n.w) * 0.5f;
    float F1r = c1 * (n.x - n.z) * 0.5f;
    float F1i = -(c1 * (n.y - n.w) * 0.5f);
    float F2  = c2 * (n.x - n.y + n.z - n.w) * 0.5f;
    float r0 = 0.5f * (F0 + 2.f*F1r + F2);
    float r1 = 0.5f * (F0 - 2.f*F1i - F2);
    float r2 = 0.5f * (F0 - 2.f*F1r + F2);
    float r3 = 0.5f * (F0 + 2.f*F1i - F2);

    const int t0 = fb * 4;
    float s0a = 0.f, s1a = 0.f, s2a = 0.f, s3a = 0.f;
    if (t0 < 256) {                      // head: freq=f0, amp=a0
      const float tp = (float)(t0 + 1) * 0.5f;
      #pragma unroll 4
      for (int o = 0; o < 32; ++o) {
        float f0 = fqv[o*32], am = al[o*32];
        float hf = 0.5f * f0;
        float v0 = tp * f0, v1 = v0 + hf, v2 = v1 + hf, v3 = v2 + hf;
        s0a += am * sin_rev(v0 - floorf(v0));
        s1a += am * sin_rev(v1 - floorf(v1));
        s2a += am * sin_rev(v2 - floorf(v2));
        s3a += am * sin_rev(v3 - floorf(v3));
      }
    } else if (t0 >= 16128) {            // tail: freq=f31, amp=a31
      const float tp = (float)(t0 - 16127) * 0.5f;
      #pragma unroll 4
      for (int o = 0; o < 32; ++o) {
        float f0 = fqv[o*32 + 31], am = al[o*32 + 31], p = pl[o*32 + 31];
        float hf = 0.5f * f0;
        float v0 = p + tp * f0, v1 = v0 + hf, v2 = v1 + hf, v3 = v2 + hf;
        s0a += am * sin_rev(v0 - floorf(v0));
        s1a += am * sin_rev(v1 - floorf(v1));
        s2a += am * sin_rev(v2 - floorf(v2));
        s3a += am * sin_rev(v3 - floorf(v3));
      }
    } else {                             // middle: same interp cell for all 4
      const int i  = (t0 - 256) >> 9;
      const int m0 = (t0 - 256) & 511;
      float mm[4], fa[4], mq[4];
      #pragma unroll
      for (int js = 0; js < 4; ++js) {
        float mmv = (float)(m0 + 1 + js);
        mm[js] = mmv;
        fa[js] = ((float)(m0 + js) + 0.5f) * (1.f/512.f);
        mq[js] = mmv * mmv * (1.f/1024.f);
      }
      #pragma unroll 4
      for (int o = 0; o < 32; ++o) {
        float f0 = fqv[o*32 + i], f1 = fqv[o*32 + i + 1];
        float a0 = al[o*32 + i],  a1 = al[o*32 + i + 1];
        float p  = pl[o*32 + i];
        float df = f1 - f0, da = a1 - a0;
        #pragma unroll
        for (int js = 0; js < 4; ++js) {
          float av   = fmaf(da, fa[js], a0);
          float part = fmaf(df, mq[js], mm[js] * f0);
          float v    = fmaf(part, 0.5f, p);
          float fr   = v - floorf(v);
          float sv   = av * sin_rev(fr);
          if      (js == 0) s0a += sv;
          else if (js == 1) s1a += sv;
          else if (js == 2) s2a += sv;
          else              s3a += sv;
        }
      }
    }
    float4 res = make_float4(s0a + r0, s1a + r1, s2a + r2, s3a + r3);
    *(float4*)(out + ((size_t)b*4096 + fb)*4) = res;
  }
}

// ---------------------------------------------------------------------------
extern "C" void kernel_launch(void* const* d_in, const int* in_sizes, int n_in,
                              void* d_out, int out_size, void* d_ws, size_t ws_size,
                              hipStream_t stream) {
  (void)in_sizes; (void)n_in; (void)out_size; (void)ws_size;
  const float* x     = (const float*)d_in[0];
  const float* noise = (const float*)d_in[1];
  const float* net_w = (const float*)d_in[2];
  const float* net_b = (const float*)d_in[3];
  const float* fin_w = (const float*)d_in[4];
  const float* fin_b = (const float*)d_in[5];
  const float* amp_w = (const float*)d_in[6];
  const float* amp_b = (const float*)d_in[7];
  const float* frq_w = (const float*)d_in[8];
  const float* frq_b = (const float*)d_in[9];
  const float* nzi_w = (const float*)d_in[10];
  const float* nzi_b = (const float*)d_in[11];
  const float* nzu_w = (const float*)d_in[12];
  const float* nzu_b = (const float*)d_in[13];
  const float* nzf_w = (const float*)d_in[14];
  const float* nzf_b = (const float*)d_in[15];
  float* out = (float*)d_out;

  // workspace (~20 MiB)
  short* y3    = (short*)d_ws;                       // 64*256*64
  short* y6    = y3 + (size_t)64*256*64;             // 64*2048*64
  short* wfold = y6 + (size_t)64*2048*64;            // 7*16384
  float* wtF4  = (float*)(wfold + 7*16384);          // 5*4096*4 = 81920
  float* awfwT = wtF4 + 81920;                       // 4096
  float* nzT   = awfwT + 4096;                       // 4096
  float* ampv  = nzT + 4096;                         // 65536
  float* frqv  = ampv + 65536;
  float* phv   = frqv + 65536;

  prep_kernel<<<dim3(560), dim3(256), 0, stream>>>(
      net_w, fin_w, amp_w, frq_w, nzi_w, nzu_w, wtF4, awfwT, nzT, wfold);

  z_front<<<dim3(64), dim3(512), 0, stream>>>(
      x, wtF4, net_b, fin_b, awfwT, amp_b, frq_b, nzT, nzi_b,
      wfold, nzu_b, (unsigned short*)y3, ampv, frqv, phv);

  up345<<<dim3(8, 64), dim3(256), 0, stream>>>(
      (unsigned short*)y3, (unsigned short*)y6, wfold, nzu_b);

  final_fused<<<dim3(16, 64), dim3(256), 0, stream>>>(
      (unsigned short*)y6, wfold + 6*16384, nzu_b + 6*64,
      nzf_w, nzf_b, noise, ampv, frqv, phv, out);
}